// Round 1
// baseline (727.576 us; speedup 1.0000x reference)
//
#include <hip/hip_runtime.h>
#include <hip/hip_bf16.h>
#include <math.h>

#define N_NODES 50000
#define N_EDGES 800000
#define NEG 0.2f

// ============================ CSR build ============================
__global__ void k_hist(const int* __restrict__ dst, int* __restrict__ deg, int E) {
    int e = blockIdx.x * 256 + threadIdx.x;
    if (e < E) atomicAdd(&deg[dst[e]], 1);
}

__global__ void k_chunksum(const int* __restrict__ deg, int* __restrict__ csum, int n) {
    __shared__ int s[256];
    int i = blockIdx.x * 256 + threadIdx.x;
    s[threadIdx.x] = (i < n) ? deg[i] : 0;
    __syncthreads();
    for (int off = 128; off > 0; off >>= 1) {
        if (threadIdx.x < off) s[threadIdx.x] += s[threadIdx.x + off];
        __syncthreads();
    }
    if (threadIdx.x == 0) csum[blockIdx.x] = s[0];
}

__global__ void k_scanchunks(const int* __restrict__ csum, int* __restrict__ coff,
                             int nch, int* __restrict__ rp, int n, int E) {
    __shared__ int s[256];
    int t = threadIdx.x;
    int v = (t < nch) ? csum[t] : 0;
    s[t] = v; __syncthreads();
    for (int off = 1; off < 256; off <<= 1) {
        int x = (t >= off) ? s[t - off] : 0;
        __syncthreads();
        s[t] += x;
        __syncthreads();
    }
    coff[t] = s[t] - v;          // exclusive prefix of chunk sums
    if (t == 0) rp[n] = E;
}

__global__ void k_scatter_rp(const int* __restrict__ deg, const int* __restrict__ coff,
                             int* __restrict__ rp, int n) {
    __shared__ int s[256];
    int i = blockIdx.x * 256 + threadIdx.x;
    int v = (i < n) ? deg[i] : 0;
    s[threadIdx.x] = v; __syncthreads();
    for (int off = 1; off < 256; off <<= 1) {
        int x = (threadIdx.x >= off) ? s[threadIdx.x - off] : 0;
        __syncthreads();
        s[threadIdx.x] += x;
        __syncthreads();
    }
    if (i < n) rp[i] = coff[blockIdx.x] + s[threadIdx.x] - v;   // exclusive
}

__global__ void k_initcur(const int* __restrict__ rp, int* __restrict__ cur, int n) {
    int i = blockIdx.x * 256 + threadIdx.x;
    if (i < n) cur[i] = rp[i];
}

__global__ void k_fill(const int* __restrict__ src, const int* __restrict__ dst,
                       int* __restrict__ cur, int* __restrict__ esrc, int E) {
    int e = blockIdx.x * 256 + threadIdx.x;
    if (e < E) {
        int p = atomicAdd(&cur[dst[e]], 1);
        esrc[p] = src[e];
    }
}

// ============================ fp32 GEMM ============================
// C[M,Nc] = A[M,K] @ B[K,Nc]; optional bias + relu. 128x128 tile, 8x8 microtile.
#define BM 128
#define BN 128
#define BK 16
__global__ __launch_bounds__(256) void gemm_f32(
    const float* __restrict__ A, const float* __restrict__ B, float* __restrict__ C,
    int M, int Nc, int K, const float* __restrict__ bias, int act)
{
    __shared__ float As[BK][BM + 4];
    __shared__ float Bs[BK][BN + 4];
    const int tid = threadIdx.x;
    const int bm = blockIdx.x * BM;
    const int bn = blockIdx.y * BN;
    const int tx = tid & 15, ty = tid >> 4;

    float acc[8][8];
    for (int i = 0; i < 8; ++i)
        for (int j = 0; j < 8; ++j) acc[i][j] = 0.f;

    for (int k0 = 0; k0 < K; k0 += BK) {
        {   // A tile: 128 rows x 16 k; 2 threads per row, 8 floats each
            int r = tid >> 1;
            int c = (tid & 1) * 8;
            int gr = bm + r;
            float4 v0 = {0,0,0,0}, v1 = {0,0,0,0};
            if (gr < M) {
                const float* ap = A + (size_t)gr * K + k0 + c;
                v0 = *(const float4*)ap;
                v1 = *(const float4*)(ap + 4);
            }
            As[c+0][r] = v0.x; As[c+1][r] = v0.y; As[c+2][r] = v0.z; As[c+3][r] = v0.w;
            As[c+4][r] = v1.x; As[c+5][r] = v1.y; As[c+6][r] = v1.z; As[c+7][r] = v1.w;
        }
        {   // B tile: 16 k-rows x 128 cols; 16 threads per k-row, 8 floats each
            int kr = tid >> 4;
            int cc = (tid & 15) * 8;
            int gc = bn + cc;
            const float* bp = B + (size_t)(k0 + kr) * Nc + gc;
            float4 v0 = {0,0,0,0}, v1 = {0,0,0,0};
            if (gc + 7 < Nc) {
                v0 = *(const float4*)bp;
                v1 = *(const float4*)(bp + 4);
            } else {
                float t[8] = {0,0,0,0,0,0,0,0};
                for (int i = 0; i < 8; ++i) if (gc + i < Nc) t[i] = bp[i];
                v0.x=t[0]; v0.y=t[1]; v0.z=t[2]; v0.w=t[3];
                v1.x=t[4]; v1.y=t[5]; v1.z=t[6]; v1.w=t[7];
            }
            *(float4*)&Bs[kr][cc]     = v0;
            *(float4*)&Bs[kr][cc + 4] = v1;
        }
        __syncthreads();
        #pragma unroll
        for (int kk = 0; kk < BK; ++kk) {
            float a[8], b[8];
            *(float4*)&a[0] = *(const float4*)&As[kk][ty * 8];
            *(float4*)&a[4] = *(const float4*)&As[kk][ty * 8 + 4];
            *(float4*)&b[0] = *(const float4*)&Bs[kk][tx * 8];
            *(float4*)&b[4] = *(const float4*)&Bs[kk][tx * 8 + 4];
            #pragma unroll
            for (int i = 0; i < 8; ++i)
                #pragma unroll
                for (int j = 0; j < 8; ++j)
                    acc[i][j] += a[i] * b[j];
        }
        __syncthreads();
    }
    // epilogue (Nc is a multiple of 8 in all our calls)
    for (int i = 0; i < 8; ++i) {
        int gr = bm + ty * 8 + i;
        if (gr >= M) continue;
        for (int j = 0; j < 8; j += 4) {
            int gc = bn + tx * 8 + j;
            if (gc >= Nc) continue;
            float4 o;
            o.x = acc[i][j+0]; o.y = acc[i][j+1]; o.z = acc[i][j+2]; o.w = acc[i][j+3];
            if (bias) {
                const float4 bv = *(const float4*)(bias + gc);
                o.x += bv.x; o.y += bv.y; o.z += bv.z; o.w += bv.w;
            }
            if (act == 1) {
                o.x = fmaxf(o.x, 0.f); o.y = fmaxf(o.y, 0.f);
                o.z = fmaxf(o.z, 0.f); o.w = fmaxf(o.w, 0.f);
            }
            *(float4*)(C + (size_t)gr * Nc + gc) = o;
        }
    }
}

// ============================ misc node kernels ============================
// concat [relu(x@Wx+bx), z] then L2-normalize -> hbuf [N,128]; one wave per node
__global__ __launch_bounds__(256) void k_norm(const float* __restrict__ h0, const float* __restrict__ z,
                                              float* __restrict__ hbuf, int n) {
    int wid = (blockIdx.x * blockDim.x + threadIdx.x) >> 6;
    int lane = threadIdx.x & 63;
    if (wid >= n) return;
    float v = h0[(size_t)wid * 64 + lane];
    float zl = z[lane];
    float ss = v * v + zl * zl;
    #pragma unroll
    for (int off = 32; off > 0; off >>= 1) ss += __shfl_xor(ss, off, 64);
    float inv = 1.f / (sqrtf(ss) + 1e-6f);
    hbuf[(size_t)wid * 128 + lane]      = v * inv;
    hbuf[(size_t)wid * 128 + 64 + lane] = zl * inv;
}

// el[n,h] = sum_d feat[n,h,d]*al[h,d]; er likewise. one wave per node, 256 cols.
__global__ __launch_bounds__(256) void k_eler256(const float* __restrict__ feat,
                                                 const float* __restrict__ al, const float* __restrict__ ar,
                                                 float* __restrict__ el, float* __restrict__ er, int n) {
    int wid = (blockIdx.x * blockDim.x + threadIdx.x) >> 6;
    int lane = threadIdx.x & 63;
    if (wid >= n) return;
    int head = lane >> 5;
    float4 f = ((const float4*)feat)[(size_t)wid * 64 + lane];
    float4 a = ((const float4*)al)[lane];
    float4 r = ((const float4*)ar)[lane];
    float pe = f.x*a.x + f.y*a.y + f.z*a.z + f.w*a.w;
    float pr = f.x*r.x + f.y*r.y + f.z*r.z + f.w*r.w;
    #pragma unroll
    for (int off = 16; off > 0; off >>= 1) {
        pe += __shfl_xor(pe, off, 64);
        pr += __shfl_xor(pr, off, 64);
    }
    if ((lane & 31) == 0) {
        el[(size_t)wid * 2 + head] = pe;
        er[(size_t)wid * 2 + head] = pr;
    }
}

// final layer: 1 head, 32 dims (feat is cols 0..31 of packed [N,64])
__global__ __launch_bounds__(256) void k_elerf(const float* __restrict__ pk,
                                               const float* __restrict__ alf, const float* __restrict__ arf,
                                               float* __restrict__ elf, float* __restrict__ erf, int n) {
    int wid = (blockIdx.x * blockDim.x + threadIdx.x) >> 6;
    int lane = threadIdx.x & 63;
    if (wid >= n) return;
    float f = (lane < 32) ? pk[(size_t)wid * 64 + lane] : 0.f;
    float a = (lane < 32) ? alf[lane] : 0.f;
    float r = (lane < 32) ? arf[lane] : 0.f;
    float pe = f * a, pr = f * r;
    #pragma unroll
    for (int off = 16; off > 0; off >>= 1) {
        pe += __shfl_xor(pe, off, 64);
        pr += __shfl_xor(pr, off, 64);
    }
    if (lane == 0) { elf[wid] = pe; erf[wid] = pr; }
}

__global__ void k_pack(const float* __restrict__ Wf, const float* __restrict__ rWf, float* __restrict__ Wfr) {
    int i = blockIdx.x * 256 + threadIdx.x;
    if (i < 256 * 64) {
        int k = i >> 6, j = i & 63;
        Wfr[i] = (j < 32) ? Wf[k * 32 + j] : rWf[k * 32 + (j - 32)];
    }
}

// ============================ edge aggregation ============================
// One wave per dst node; online softmax over in-edges; lane covers 4 cols (head = lane>>5).
// RES=1: identity residual read from outp row (safe: each wave touches only its own row).
template<int RES>
__global__ __launch_bounds__(256) void k_edge256(
    const float* __restrict__ feat, const float* __restrict__ el, const float* __restrict__ er,
    const float* __restrict__ bias, const int* __restrict__ rp, const int* __restrict__ esrc,
    float* __restrict__ outp, int n)
{
    int wid = (blockIdx.x * blockDim.x + threadIdx.x) >> 6;
    int lane = threadIdx.x & 63;
    if (wid >= n) return;
    int head = lane >> 5;
    int rs = rp[wid], re = rp[wid + 1];
    float ern = er[(size_t)wid * 2 + head];
    float m = -INFINITY, den = 0.f;
    float ax = 0.f, ay = 0.f, az = 0.f, aw = 0.f;
    const float4* f4 = (const float4*)feat;
    for (int e = rs; e < re; ++e) {
        int s = esrc[e];
        float x = el[(size_t)s * 2 + head] + ern;
        x = (x > 0.f) ? x : NEG * x;                 // leaky relu
        float4 v = f4[(size_t)s * 64 + lane];
        float mn = fmaxf(m, x);
        float corr = __expf(m - mn);
        float wgt  = __expf(x - mn);
        den = den * corr + wgt;
        ax = ax * corr + wgt * v.x;
        ay = ay * corr + wgt * v.y;
        az = az * corr + wgt * v.z;
        aw = aw * corr + wgt * v.w;
        m = mn;
    }
    float inv = (re > rs) ? 1.f / den : 0.f;
    int c0 = lane * 4;
    float4 bv = *(const float4*)(bias + c0);
    float rx = 0.f, ry = 0.f, rz = 0.f, rw = 0.f;
    if (RES) {
        float4 rv = *(const float4*)(outp + (size_t)wid * 256 + c0);
        rx = rv.x; ry = rv.y; rz = rv.z; rw = rv.w;
    }
    float ox = ax * inv + bv.x + rx;
    float oy = ay * inv + bv.y + ry;
    float oz = az * inv + bv.z + rz;
    float ow = aw * inv + bv.w + rw;
    // elu
    ox = (ox > 0.f) ? ox : expm1f(ox);
    oy = (oy > 0.f) ? oy : expm1f(oy);
    oz = (oz > 0.f) ? oz : expm1f(oz);
    ow = (ow > 0.f) ? ow : expm1f(ow);
    float4 o; o.x = ox; o.y = oy; o.z = oz; o.w = ow;
    *((float4*)(outp + (size_t)wid * 256 + c0)) = o;
}

// final layer: 32 cols, 1 head; logits = attn_sum + resid + bf (mean over 1 head = identity)
__global__ __launch_bounds__(256) void k_edgef(
    const float* __restrict__ pk, const float* __restrict__ elf, const float* __restrict__ erf,
    const float* __restrict__ bf, const int* __restrict__ rp, const int* __restrict__ esrc,
    float* __restrict__ outp, int n)
{
    int wid = (blockIdx.x * blockDim.x + threadIdx.x) >> 6;
    int lane = threadIdx.x & 63;
    if (wid >= n) return;
    int c = lane & 31;
    int rs = rp[wid], re = rp[wid + 1];
    float ern = erf[wid];
    float m = -INFINITY, den = 0.f, acc = 0.f;
    for (int e = rs; e < re; ++e) {
        int s = esrc[e];
        float x = elf[s] + ern;
        x = (x > 0.f) ? x : NEG * x;
        float v = pk[(size_t)s * 64 + c];
        float mn = fmaxf(m, x);
        float corr = __expf(m - mn);
        float wgt  = __expf(x - mn);
        den = den * corr + wgt;
        acc = acc * corr + wgt * v;
        m = mn;
    }
    float inv = (re > rs) ? 1.f / den : 0.f;
    if (lane < 32)
        outp[(size_t)wid * 32 + c] = acc * inv + pk[(size_t)wid * 64 + 32 + c] + bf[c];
}

// ============================ launch ============================
extern "C" void kernel_launch(void* const* d_in, const int* in_sizes, int n_in,
                              void* d_out, int out_size, void* d_ws, size_t ws_size,
                              hipStream_t stream) {
    const float* inputs = (const float*)d_in[0];
    const float* z      = (const float*)d_in[1];
    const int*   src    = (const int*)d_in[2];
    const int*   dst    = (const int*)d_in[3];
    const float* Wx  = (const float*)d_in[4];
    const float* bx  = (const float*)d_in[5];
    const float* W0  = (const float*)d_in[6];
    const float* al0 = (const float*)d_in[7];
    const float* ar0 = (const float*)d_in[8];
    const float* b0  = (const float*)d_in[9];
    const float* W1  = (const float*)d_in[10];
    const float* al1 = (const float*)d_in[11];
    const float* ar1 = (const float*)d_in[12];
    const float* b1  = (const float*)d_in[13];
    const float* Wf  = (const float*)d_in[14];
    const float* alf = (const float*)d_in[15];
    const float* arf = (const float*)d_in[16];
    const float* bf  = (const float*)d_in[17];
    const float* rWf = (const float*)d_in[18];
    float* out = (float*)d_out;

    const int N = N_NODES, E = N_EDGES;

    char* w = (char*)d_ws;
    auto alloc = [&](size_t bytes) -> char* {
        char* p = w;
        w += (bytes + 255) & ~(size_t)255;
        return p;
    };
    float* hbuf = (float*)alloc((size_t)N * 128 * 4);   // normalized input features
    float* Abuf = (float*)alloc((size_t)N * 256 * 4);   // h1, then h2 (in-place)
    float* Bbuf = (float*)alloc((size_t)N * 256 * 4);   // feat0, then feat1
    float* pk   = (float*)alloc((size_t)N * 64 * 4);    // h0 pre-norm, later featf|resid
    float* elb  = (float*)alloc((size_t)N * 2 * 4);
    float* erb  = (float*)alloc((size_t)N * 2 * 4);
    float* Wfr  = (float*)alloc((size_t)256 * 64 * 4);
    int* rp   = (int*)alloc((size_t)(N + 1) * 4);
    int* deg  = (int*)alloc((size_t)N * 4);
    int* cur  = (int*)alloc((size_t)N * 4);
    int* csum = (int*)alloc(256 * 4);
    int* coff = (int*)alloc(256 * 4);
    int* esrc = (int*)alloc((size_t)E * 4);

    // ---- CSR by dst (same every call; rebuilt deterministically) ----
    hipMemsetAsync(deg, 0, (size_t)N * 4, stream);
    k_hist<<<(E + 255) / 256, 256, 0, stream>>>(dst, deg, E);
    int nch = (N + 255) / 256;
    k_chunksum<<<nch, 256, 0, stream>>>(deg, csum, N);
    k_scanchunks<<<1, 256, 0, stream>>>(csum, coff, nch, rp, N, E);
    k_scatter_rp<<<nch, 256, 0, stream>>>(deg, coff, rp, N);
    k_initcur<<<(N + 255) / 256, 256, 0, stream>>>(rp, cur, N);
    k_fill<<<(E + 255) / 256, 256, 0, stream>>>(src, dst, cur, esrc, E);

    int nwb = (N + 3) / 4;   // node-per-wave kernels: 4 waves / 256-thread block

    // ---- x_to_h: relu(X@Wx+bx) -> concat z -> normalize ----
    {
        dim3 g((N + BM - 1) / BM, 1);
        gemm_f32<<<g, 256, 0, stream>>>(inputs, Wx, pk, N, 64, 256, bx, 1);
        k_norm<<<nwb, 256, 0, stream>>>(pk, z, hbuf, N);
    }
    // ---- GAT layer 0: [N,128] -> feat [N,256], edge softmax, elu ----
    {
        dim3 g((N + BM - 1) / BM, 2);
        gemm_f32<<<g, 256, 0, stream>>>(hbuf, W0, Bbuf, N, 256, 128, nullptr, 0);
        k_eler256<<<nwb, 256, 0, stream>>>(Bbuf, al0, ar0, elb, erb, N);
        k_edge256<0><<<nwb, 256, 0, stream>>>(Bbuf, elb, erb, b0, rp, esrc, Abuf, N);
    }
    // ---- GAT layer 1: identity residual ----
    {
        dim3 g((N + BM - 1) / BM, 2);
        gemm_f32<<<g, 256, 0, stream>>>(Abuf, W1, Bbuf, N, 256, 256, nullptr, 0);
        k_eler256<<<nwb, 256, 0, stream>>>(Bbuf, al1, ar1, elb, erb, N);
        k_edge256<1><<<nwb, 256, 0, stream>>>(Bbuf, elb, erb, b1, rp, esrc, Abuf, N);
    }
    // ---- final GAT: [N,256] -> 32, linear residual; pack Wf|resWf ----
    {
        k_pack<<<(256 * 64 + 255) / 256, 256, 0, stream>>>(Wf, rWf, Wfr);
        dim3 g((N + BM - 1) / BM, 1);
        gemm_f32<<<g, 256, 0, stream>>>(Abuf, Wfr, pk, N, 64, 256, nullptr, 0);
        k_elerf<<<nwb, 256, 0, stream>>>(pk, alf, arf, elb, erb, N);
        k_edgef<<<nwb, 256, 0, stream>>>(pk, elb, erb, bf, rp, esrc, out, N);
    }
}

// Round 2
// 458.253 us; speedup vs baseline: 1.5877x; 1.5877x over previous
//
#include <hip/hip_runtime.h>
#include <hip/hip_bf16.h>
#include <math.h>

#define N_NODES 50000
#define N_EDGES 800000
#define NEG 0.2f

typedef __attribute__((ext_vector_type(4))) float f32x4;
typedef __attribute__((ext_vector_type(8))) short bf16x8;

__device__ __forceinline__ float bf2f(ushort u) {
    union { uint i; float f; } t; t.i = ((uint)u) << 16; return t.f;
}
__device__ __forceinline__ ushort f2bf(float f) {
    union { float f; uint i; } t; t.f = f;
    uint i = t.i;
    uint r = (i + 0x7FFFu + ((i >> 16) & 1u)) >> 16;   // RNE
    return (ushort)r;
}

// ============================ CSR build ============================
__global__ void k_hist(const int* __restrict__ dst, int* __restrict__ deg, int E) {
    int e = blockIdx.x * 256 + threadIdx.x;
    if (e < E) atomicAdd(&deg[dst[e]], 1);
}

__global__ void k_chunksum(const int* __restrict__ deg, int* __restrict__ csum, int n) {
    __shared__ int s[256];
    int i = blockIdx.x * 256 + threadIdx.x;
    s[threadIdx.x] = (i < n) ? deg[i] : 0;
    __syncthreads();
    for (int off = 128; off > 0; off >>= 1) {
        if (threadIdx.x < off) s[threadIdx.x] += s[threadIdx.x + off];
        __syncthreads();
    }
    if (threadIdx.x == 0) csum[blockIdx.x] = s[0];
}

__global__ void k_scanchunks(const int* __restrict__ csum, int* __restrict__ coff,
                             int nch, int* __restrict__ rp, int n, int E) {
    __shared__ int s[256];
    int t = threadIdx.x;
    int v = (t < nch) ? csum[t] : 0;
    s[t] = v; __syncthreads();
    for (int off = 1; off < 256; off <<= 1) {
        int x = (t >= off) ? s[t - off] : 0;
        __syncthreads();
        s[t] += x;
        __syncthreads();
    }
    coff[t] = s[t] - v;          // exclusive prefix of chunk sums
    if (t == 0) rp[n] = E;
}

__global__ void k_scatter_rp(const int* __restrict__ deg, const int* __restrict__ coff,
                             int* __restrict__ rp, int n) {
    __shared__ int s[256];
    int i = blockIdx.x * 256 + threadIdx.x;
    int v = (i < n) ? deg[i] : 0;
    s[threadIdx.x] = v; __syncthreads();
    for (int off = 1; off < 256; off <<= 1) {
        int x = (threadIdx.x >= off) ? s[threadIdx.x - off] : 0;
        __syncthreads();
        s[threadIdx.x] += x;
        __syncthreads();
    }
    if (i < n) rp[i] = coff[blockIdx.x] + s[threadIdx.x] - v;   // exclusive
}

__global__ void k_initcur(const int* __restrict__ rp, int* __restrict__ cur, int n) {
    int i = blockIdx.x * 256 + threadIdx.x;
    if (i < n) cur[i] = rp[i];
}

__global__ void k_fill(const int* __restrict__ src, const int* __restrict__ dst,
                       int* __restrict__ cur, int* __restrict__ esrc, int E) {
    int e = blockIdx.x * 256 + threadIdx.x;
    if (e < E) {
        int p = atomicAdd(&cur[dst[e]], 1);
        esrc[p] = src[e];
    }
}

// ============================ weight prep ============================
// Bt[n][k] = bf16(W[k][n])
__global__ void k_transp(const float* __restrict__ W, ushort* __restrict__ Bt, int K, int Nc) {
    int i = blockIdx.x * 256 + threadIdx.x;
    if (i < K * Nc) {
        int k = i / Nc, n = i % Nc;
        Bt[(size_t)n * K + k] = f2bf(W[i]);
    }
}

// BtF[n][k]: n<32 -> Wf[k][n], else rWf[k][n-32]  (64 x 256)
__global__ void k_packT(const float* __restrict__ Wf, const float* __restrict__ rWf,
                        ushort* __restrict__ BtF) {
    int i = blockIdx.x * 256 + threadIdx.x;
    if (i < 64 * 256) {
        int n = i >> 8, k = i & 255;
        float v = (n < 32) ? Wf[k * 32 + n] : rWf[k * 32 + (n - 32)];
        BtF[i] = f2bf(v);
    }
}

// ============================ bf16 MFMA GEMM ============================
// C[M,Nc] = A[M,K] @ B[K,Nc]; B given transposed+bf16: Bt[Nc][K].
// A: f32 (converted on stage) or bf16. 16x16x32 MFMA, BK=32.
template<bool A_F32, bool OUT_BF16, int ACT, int WR, int WC, int WM, int WN>
__global__ __launch_bounds__(256) void gemm_mfma(
    const void* __restrict__ Aptr, const ushort* __restrict__ Bt, void* __restrict__ Cptr,
    int M, int Nc, int K, const float* __restrict__ bias)
{
    constexpr int BM = WR * WM * 16;
    constexpr int BN = WC * WN * 16;
    constexpr int BK = 32;
    constexpr int LDA = BK + 8;          // pad to break bank conflicts
    __shared__ ushort As[BM][LDA];
    __shared__ ushort Bs[BN][LDA];

    const int tid = threadIdx.x;
    const int bm = blockIdx.x * BM;
    const int bn = blockIdx.y * BN;
    const int lane = tid & 63;
    const int w = tid >> 6;
    const int wr = w / WC, wc = w % WC;
    const int fr = lane & 15;
    const int kg = lane >> 4;

    f32x4 acc[WM][WN];
    #pragma unroll
    for (int i = 0; i < WM; ++i)
        #pragma unroll
        for (int j = 0; j < WN; ++j) acc[i][j] = (f32x4){0.f, 0.f, 0.f, 0.f};

    const float*  Af = (const float*)Aptr;
    const ushort* Ab = (const ushort*)Aptr;

    for (int k0 = 0; k0 < K; k0 += BK) {
        // ---- stage A tile: BM rows x BK cols, chunks of 4 elems ----
        constexpr int ACH = BM * (BK / 4);
        #pragma unroll
        for (int c = tid; c < ACH; c += 256) {
            int r = c >> 3;            // 8 chunks per row
            int ko = (c & 7) * 4;
            int gr = bm + r;
            ushort4 o = {0, 0, 0, 0};
            if (gr < M) {
                if (A_F32) {
                    float4 v = *(const float4*)(Af + (size_t)gr * K + k0 + ko);
                    o.x = f2bf(v.x); o.y = f2bf(v.y); o.z = f2bf(v.z); o.w = f2bf(v.w);
                } else {
                    o = *(const ushort4*)(Ab + (size_t)gr * K + k0 + ko);
                }
            }
            *(ushort4*)&As[r][ko] = o;
        }
        // ---- stage B tile: BN rows x BK cols from Bt[Nc][K] ----
        constexpr int BCH = BN * (BK / 4);
        #pragma unroll
        for (int c = tid; c < BCH; c += 256) {
            int r = c >> 3;
            int ko = (c & 7) * 4;
            *(ushort4*)&Bs[r][ko] = *(const ushort4*)(Bt + (size_t)(bn + r) * K + k0 + ko);
        }
        __syncthreads();

        bf16x8 a[WM], b[WN];
        #pragma unroll
        for (int m = 0; m < WM; ++m)
            a[m] = *(const bf16x8*)&As[wr * WM * 16 + m * 16 + fr][kg * 8];
        #pragma unroll
        for (int n = 0; n < WN; ++n)
            b[n] = *(const bf16x8*)&Bs[wc * WN * 16 + n * 16 + fr][kg * 8];
        #pragma unroll
        for (int m = 0; m < WM; ++m)
            #pragma unroll
            for (int n = 0; n < WN; ++n)
                acc[m][n] = __builtin_amdgcn_mfma_f32_16x16x32_bf16(a[m], b[n], acc[m][n], 0, 0, 0);
        __syncthreads();
    }

    // ---- epilogue: C/D layout col=lane&15, row=(lane>>4)*4+j ----
    float*  Cf = (float*)Cptr;
    ushort* Cb = (ushort*)Cptr;
    #pragma unroll
    for (int m = 0; m < WM; ++m) {
        #pragma unroll
        for (int n = 0; n < WN; ++n) {
            int col = bn + wc * WN * 16 + n * 16 + fr;
            float bv = bias ? bias[col] : 0.f;
            #pragma unroll
            for (int j = 0; j < 4; ++j) {
                int row = bm + wr * WM * 16 + m * 16 + kg * 4 + j;
                if (row < M) {
                    float o = acc[m][n][j] + bv;
                    if (ACT == 1) o = fmaxf(o, 0.f);
                    if (OUT_BF16) Cb[(size_t)row * Nc + col] = f2bf(o);
                    else          Cf[(size_t)row * Nc + col] = o;
                }
            }
        }
    }
}

// ============================ misc node kernels ============================
// concat [relu(x@Wx+bx), z] then L2-normalize -> hbuf bf16 [N,128]; one wave per node
__global__ __launch_bounds__(256) void k_norm(const float* __restrict__ h0, const float* __restrict__ z,
                                              ushort* __restrict__ hbuf, int n) {
    int wid = (blockIdx.x * blockDim.x + threadIdx.x) >> 6;
    int lane = threadIdx.x & 63;
    if (wid >= n) return;
    float v = h0[(size_t)wid * 64 + lane];
    float zl = z[lane];
    float ss = v * v + zl * zl;
    #pragma unroll
    for (int off = 32; off > 0; off >>= 1) ss += __shfl_xor(ss, off, 64);
    float inv = 1.f / (sqrtf(ss) + 1e-6f);
    hbuf[(size_t)wid * 128 + lane]      = f2bf(v * inv);
    hbuf[(size_t)wid * 128 + 64 + lane] = f2bf(zl * inv);
}

// el/er from bf16 feat [N,256]; one wave per node; head = lane>>5
__global__ __launch_bounds__(256) void k_eler256(const ushort* __restrict__ feat,
                                                 const float* __restrict__ al, const float* __restrict__ ar,
                                                 float* __restrict__ el, float* __restrict__ er, int n) {
    int wid = (blockIdx.x * blockDim.x + threadIdx.x) >> 6;
    int lane = threadIdx.x & 63;
    if (wid >= n) return;
    int head = lane >> 5;
    ushort4 fu = ((const ushort4*)feat)[(size_t)wid * 64 + lane];
    float4 a = ((const float4*)al)[lane];
    float4 r = ((const float4*)ar)[lane];
    float fx = bf2f(fu.x), fy = bf2f(fu.y), fz = bf2f(fu.z), fw = bf2f(fu.w);
    float pe = fx * a.x + fy * a.y + fz * a.z + fw * a.w;
    float pr = fx * r.x + fy * r.y + fz * r.z + fw * r.w;
    #pragma unroll
    for (int off = 16; off > 0; off >>= 1) {
        pe += __shfl_xor(pe, off, 64);
        pr += __shfl_xor(pr, off, 64);
    }
    if ((lane & 31) == 0) {
        el[(size_t)wid * 2 + head] = pe;
        er[(size_t)wid * 2 + head] = pr;
    }
}

// final layer: 1 head, 32 dims (pk f32 [N,64]: feat|resid)
__global__ __launch_bounds__(256) void k_elerf(const float* __restrict__ pk,
                                               const float* __restrict__ alf, const float* __restrict__ arf,
                                               float* __restrict__ elf, float* __restrict__ erf, int n) {
    int wid = (blockIdx.x * blockDim.x + threadIdx.x) >> 6;
    int lane = threadIdx.x & 63;
    if (wid >= n) return;
    float f = (lane < 32) ? pk[(size_t)wid * 64 + lane] : 0.f;
    float a = (lane < 32) ? alf[lane] : 0.f;
    float r = (lane < 32) ? arf[lane] : 0.f;
    float pe = f * a, pr = f * r;
    #pragma unroll
    for (int off = 16; off > 0; off >>= 1) {
        pe += __shfl_xor(pe, off, 64);
        pr += __shfl_xor(pr, off, 64);
    }
    if (lane == 0) { elf[wid] = pe; erf[wid] = pr; }
}

// ============================ edge aggregation ============================
// One wave per dst node; 2-stream online softmax over in-edges (ILP);
// lane covers 4 cols of 256 (bf16), head = lane>>5. Output bf16 h row (+bias, elu, optional resid).
template<int RES>
__global__ __launch_bounds__(256) void k_edge256(
    const ushort* __restrict__ feat, const float* __restrict__ el, const float* __restrict__ er,
    const float* __restrict__ bias, const int* __restrict__ rp, const int* __restrict__ esrc,
    ushort* __restrict__ outp, const ushort* __restrict__ resid, int n)
{
    int wid = (blockIdx.x * blockDim.x + threadIdx.x) >> 6;
    int lane = threadIdx.x & 63;
    if (wid >= n) return;
    int head = lane >> 5;
    int rs = rp[wid], re = rp[wid + 1];
    float ern = er[(size_t)wid * 2 + head];
    const ushort4* f4 = (const ushort4*)feat;

    float m0 = -INFINITY, d0 = 0.f, a0x = 0.f, a0y = 0.f, a0z = 0.f, a0w = 0.f;
    float m1 = -INFINITY, d1 = 0.f, a1x = 0.f, a1y = 0.f, a1z = 0.f, a1w = 0.f;

    int e = rs;
    for (; e + 1 < re; e += 2) {
        int s0 = esrc[e], s1 = esrc[e + 1];
        float x0 = el[(size_t)s0 * 2 + head] + ern;
        float x1 = el[(size_t)s1 * 2 + head] + ern;
        ushort4 v0 = f4[(size_t)s0 * 64 + lane];
        ushort4 v1 = f4[(size_t)s1 * 64 + lane];
        x0 = (x0 > 0.f) ? x0 : NEG * x0;
        x1 = (x1 > 0.f) ? x1 : NEG * x1;
        {
            float mn = fmaxf(m0, x0);
            float corr = __expf(m0 - mn), wgt = __expf(x0 - mn);
            d0 = d0 * corr + wgt;
            a0x = a0x * corr + wgt * bf2f(v0.x);
            a0y = a0y * corr + wgt * bf2f(v0.y);
            a0z = a0z * corr + wgt * bf2f(v0.z);
            a0w = a0w * corr + wgt * bf2f(v0.w);
            m0 = mn;
        }
        {
            float mn = fmaxf(m1, x1);
            float corr = __expf(m1 - mn), wgt = __expf(x1 - mn);
            d1 = d1 * corr + wgt;
            a1x = a1x * corr + wgt * bf2f(v1.x);
            a1y = a1y * corr + wgt * bf2f(v1.y);
            a1z = a1z * corr + wgt * bf2f(v1.z);
            a1w = a1w * corr + wgt * bf2f(v1.w);
            m1 = mn;
        }
    }
    if (e < re) {
        int s0 = esrc[e];
        float x0 = el[(size_t)s0 * 2 + head] + ern;
        ushort4 v0 = f4[(size_t)s0 * 64 + lane];
        x0 = (x0 > 0.f) ? x0 : NEG * x0;
        float mn = fmaxf(m0, x0);
        float corr = __expf(m0 - mn), wgt = __expf(x0 - mn);
        d0 = d0 * corr + wgt;
        a0x = a0x * corr + wgt * bf2f(v0.x);
        a0y = a0y * corr + wgt * bf2f(v0.y);
        a0z = a0z * corr + wgt * bf2f(v0.z);
        a0w = a0w * corr + wgt * bf2f(v0.w);
        m0 = mn;
    }

    float ax = 0.f, ay = 0.f, az = 0.f, aw = 0.f, inv = 0.f;
    if (re > rs) {   // stream0 is non-empty whenever deg>=1; merge (handles empty stream1)
        float mn = fmaxf(m0, m1);
        float c0 = __expf(m0 - mn), c1 = __expf(m1 - mn);
        float den = d0 * c0 + d1 * c1;
        ax = a0x * c0 + a1x * c1;
        ay = a0y * c0 + a1y * c1;
        az = a0z * c0 + a1z * c1;
        aw = a0w * c0 + a1w * c1;
        inv = 1.f / den;
    }

    int c0i = lane * 4;
    float4 bv = *(const float4*)(bias + c0i);
    float rx = 0.f, ry = 0.f, rz = 0.f, rw = 0.f;
    if (RES) {
        ushort4 rv = ((const ushort4*)resid)[(size_t)wid * 64 + lane];
        rx = bf2f(rv.x); ry = bf2f(rv.y); rz = bf2f(rv.z); rw = bf2f(rv.w);
    }
    float ox = ax * inv + bv.x + rx;
    float oy = ay * inv + bv.y + ry;
    float oz = az * inv + bv.z + rz;
    float ow = aw * inv + bv.w + rw;
    ox = (ox > 0.f) ? ox : expm1f(ox);
    oy = (oy > 0.f) ? oy : expm1f(oy);
    oz = (oz > 0.f) ? oz : expm1f(oz);
    ow = (ow > 0.f) ? ow : expm1f(ow);
    ushort4 o;
    o.x = f2bf(ox); o.y = f2bf(oy); o.z = f2bf(oz); o.w = f2bf(ow);
    ((ushort4*)outp)[(size_t)wid * 64 + lane] = o;
}

// final layer: 32 cols, 1 head; logits = attn_sum + resid + bf; pk f32 [N,64] = feat|resid
__global__ __launch_bounds__(256) void k_edgef(
    const float* __restrict__ pk, const float* __restrict__ elf, const float* __restrict__ erf,
    const float* __restrict__ bf, const int* __restrict__ rp, const int* __restrict__ esrc,
    float* __restrict__ outp, int n)
{
    int wid = (blockIdx.x * blockDim.x + threadIdx.x) >> 6;
    int lane = threadIdx.x & 63;
    if (wid >= n) return;
    int c = lane & 31;
    int rs = rp[wid], re = rp[wid + 1];
    float ern = erf[wid];
    float m0 = -INFINITY, d0 = 0.f, A0 = 0.f;
    float m1 = -INFINITY, d1 = 0.f, A1 = 0.f;
    int e = rs;
    for (; e + 1 < re; e += 2) {
        int s0 = esrc[e], s1 = esrc[e + 1];
        float x0 = elf[s0] + ern;
        float x1 = elf[s1] + ern;
        float v0 = pk[(size_t)s0 * 64 + c];
        float v1 = pk[(size_t)s1 * 64 + c];
        x0 = (x0 > 0.f) ? x0 : NEG * x0;
        x1 = (x1 > 0.f) ? x1 : NEG * x1;
        {
            float mn = fmaxf(m0, x0);
            float corr = __expf(m0 - mn), wgt = __expf(x0 - mn);
            d0 = d0 * corr + wgt; A0 = A0 * corr + wgt * v0; m0 = mn;
        }
        {
            float mn = fmaxf(m1, x1);
            float corr = __expf(m1 - mn), wgt = __expf(x1 - mn);
            d1 = d1 * corr + wgt; A1 = A1 * corr + wgt * v1; m1 = mn;
        }
    }
    if (e < re) {
        int s0 = esrc[e];
        float x0 = elf[s0] + ern;
        float v0 = pk[(size_t)s0 * 64 + c];
        x0 = (x0 > 0.f) ? x0 : NEG * x0;
        float mn = fmaxf(m0, x0);
        float corr = __expf(m0 - mn), wgt = __expf(x0 - mn);
        d0 = d0 * corr + wgt; A0 = A0 * corr + wgt * v0; m0 = mn;
    }
    float acc = 0.f, inv = 0.f;
    if (re > rs) {
        float mn = fmaxf(m0, m1);
        float c0 = __expf(m0 - mn), c1 = __expf(m1 - mn);
        float den = d0 * c0 + d1 * c1;
        acc = A0 * c0 + A1 * c1;
        inv = 1.f / den;
    }
    if (lane < 32)
        outp[(size_t)wid * 32 + c] = acc * inv + pk[(size_t)wid * 64 + 32 + c] + bf[c];
}

// ============================ launch ============================
extern "C" void kernel_launch(void* const* d_in, const int* in_sizes, int n_in,
                              void* d_out, int out_size, void* d_ws, size_t ws_size,
                              hipStream_t stream) {
    const float* inputs = (const float*)d_in[0];
    const float* z      = (const float*)d_in[1];
    const int*   src    = (const int*)d_in[2];
    const int*   dst    = (const int*)d_in[3];
    const float* Wx  = (const float*)d_in[4];
    const float* bx  = (const float*)d_in[5];
    const float* W0  = (const float*)d_in[6];
    const float* al0 = (const float*)d_in[7];
    const float* ar0 = (const float*)d_in[8];
    const float* b0  = (const float*)d_in[9];
    const float* W1  = (const float*)d_in[10];
    const float* al1 = (const float*)d_in[11];
    const float* ar1 = (const float*)d_in[12];
    const float* b1  = (const float*)d_in[13];
    const float* Wf  = (const float*)d_in[14];
    const float* alf = (const float*)d_in[15];
    const float* arf = (const float*)d_in[16];
    const float* bf  = (const float*)d_in[17];
    const float* rWf = (const float*)d_in[18];
    float* out = (float*)d_out;

    const int N = N_NODES, E = N_EDGES;

    char* w = (char*)d_ws;
    auto alloc = [&](size_t bytes) -> char* {
        char* p = w;
        w += (bytes + 255) & ~(size_t)255;
        return p;
    };
    ushort* hbuf = (ushort*)alloc((size_t)N * 128 * 2);   // normalized input features (bf16)
    ushort* feat = (ushort*)alloc((size_t)N * 256 * 2);   // GEMM output features (bf16), reused per layer
    ushort* h1   = (ushort*)alloc((size_t)N * 256 * 2);   // layer-0 output (bf16)
    ushort* h2   = (ushort*)alloc((size_t)N * 256 * 2);   // layer-1 output (bf16)
    float*  pk   = (float*)alloc((size_t)N * 64 * 4);     // x_to_h out, later featf|resid (f32)
    float*  elb  = (float*)alloc((size_t)N * 2 * 4);
    float*  erb  = (float*)alloc((size_t)N * 2 * 4);
    ushort* BtX  = (ushort*)alloc((size_t)64 * 256 * 2);
    ushort* Bt0  = (ushort*)alloc((size_t)256 * 128 * 2);
    ushort* Bt1  = (ushort*)alloc((size_t)256 * 256 * 2);
    ushort* BtF  = (ushort*)alloc((size_t)64 * 256 * 2);
    int* rp   = (int*)alloc((size_t)(N + 1) * 4);
    int* deg  = (int*)alloc((size_t)N * 4);
    int* cur  = (int*)alloc((size_t)N * 4);
    int* csum = (int*)alloc(256 * 4);
    int* coff = (int*)alloc(256 * 4);
    int* esrc = (int*)alloc((size_t)E * 4);

    // ---- CSR by dst ----
    hipMemsetAsync(deg, 0, (size_t)N * 4, stream);
    k_hist<<<(E + 255) / 256, 256, 0, stream>>>(dst, deg, E);
    int nch = (N + 255) / 256;
    k_chunksum<<<nch, 256, 0, stream>>>(deg, csum, N);
    k_scanchunks<<<1, 256, 0, stream>>>(csum, coff, nch, rp, N, E);
    k_scatter_rp<<<nch, 256, 0, stream>>>(deg, coff, rp, N);
    k_initcur<<<(N + 255) / 256, 256, 0, stream>>>(rp, cur, N);
    k_fill<<<(E + 255) / 256, 256, 0, stream>>>(src, dst, cur, esrc, E);

    // ---- weight transposes (bf16) ----
    k_transp<<<(256 * 64 + 255) / 256, 256, 0, stream>>>(Wx, BtX, 256, 64);
    k_transp<<<(128 * 256 + 255) / 256, 256, 0, stream>>>(W0, Bt0, 128, 256);
    k_transp<<<(256 * 256 + 255) / 256, 256, 0, stream>>>(W1, Bt1, 256, 256);
    k_packT<<<(64 * 256 + 255) / 256, 256, 0, stream>>>(Wf, rWf, BtF);

    int nwb = (N + 3) / 4;   // node-per-wave kernels: 4 waves / block
    dim3 gw((N + 127) / 128, 1);   // 128x64 GEMM grid
    dim3 gb((N + 127) / 128, 2);   // 128x128 GEMM grid (Nc=256)

    // ---- x_to_h: relu(X@Wx+bx) -> concat z -> normalize ----
    gemm_mfma<true, false, 1, 4, 1, 2, 4><<<gw, 256, 0, stream>>>(inputs, BtX, pk, N, 64, 256, bx);
    k_norm<<<nwb, 256, 0, stream>>>(pk, z, hbuf, N);

    // ---- GAT layer 0 ----
    gemm_mfma<false, true, 0, 2, 2, 4, 4><<<gb, 256, 0, stream>>>(hbuf, Bt0, feat, N, 256, 128, nullptr);
    k_eler256<<<nwb, 256, 0, stream>>>(feat, al0, ar0, elb, erb, N);
    k_edge256<0><<<nwb, 256, 0, stream>>>(feat, elb, erb, b0, rp, esrc, h1, nullptr, N);

    // ---- GAT layer 1 (identity residual) ----
    gemm_mfma<false, true, 0, 2, 2, 4, 4><<<gb, 256, 0, stream>>>(h1, Bt1, feat, N, 256, 256, nullptr);
    k_eler256<<<nwb, 256, 0, stream>>>(feat, al1, ar1, elb, erb, N);
    k_edge256<1><<<nwb, 256, 0, stream>>>(feat, elb, erb, b1, rp, esrc, h2, h1, N);

    // ---- final GAT: [N,256] -> 32 + linear residual (packed into pk f32 [N,64]) ----
    gemm_mfma<false, false, 0, 4, 1, 2, 4><<<gw, 256, 0, stream>>>(h2, BtF, pk, N, 64, 256, nullptr);
    k_elerf<<<nwb, 256, 0, stream>>>(pk, alf, arf, elb, erb, N);
    k_edgef<<<nwb, 256, 0, stream>>>(pk, elb, erb, bf, rp, esrc, out, N);
}

// Round 3
// 416.764 us; speedup vs baseline: 1.7458x; 1.0996x over previous
//
#include <hip/hip_runtime.h>
#include <hip/hip_bf16.h>
#include <math.h>

#define N_NODES 50000
#define N_EDGES 800000
#define NEG 0.2f

typedef __attribute__((ext_vector_type(4))) float f32x4;
typedef __attribute__((ext_vector_type(8))) short bf16x8;

__device__ __forceinline__ float bf2f(ushort u) {
    union { uint i; float f; } t; t.i = ((uint)u) << 16; return t.f;
}
__device__ __forceinline__ ushort f2bf(float f) {
    union { float f; uint i; } t; t.f = f;
    uint i = t.i;
    uint r = (i + 0x7FFFu + ((i >> 16) & 1u)) >> 16;   // RNE
    return (ushort)r;
}

// ============================ CSR build ============================
__global__ void k_hist(const int* __restrict__ dst, int* __restrict__ deg, int E) {
    int e = blockIdx.x * 256 + threadIdx.x;
    if (e < E) atomicAdd(&deg[dst[e]], 1);
}

__global__ void k_chunksum(const int* __restrict__ deg, int* __restrict__ csum, int n) {
    __shared__ int s[256];
    int i = blockIdx.x * 256 + threadIdx.x;
    s[threadIdx.x] = (i < n) ? deg[i] : 0;
    __syncthreads();
    for (int off = 128; off > 0; off >>= 1) {
        if (threadIdx.x < off) s[threadIdx.x] += s[threadIdx.x + off];
        __syncthreads();
    }
    if (threadIdx.x == 0) csum[blockIdx.x] = s[0];
}

__global__ void k_scanchunks(const int* __restrict__ csum, int* __restrict__ coff,
                             int nch, int* __restrict__ rp, int n, int E) {
    __shared__ int s[256];
    int t = threadIdx.x;
    int v = (t < nch) ? csum[t] : 0;
    s[t] = v; __syncthreads();
    for (int off = 1; off < 256; off <<= 1) {
        int x = (t >= off) ? s[t - off] : 0;
        __syncthreads();
        s[t] += x;
        __syncthreads();
    }
    coff[t] = s[t] - v;          // exclusive prefix of chunk sums
    if (t == 0) rp[n] = E;
}

__global__ void k_scatter_rp(const int* __restrict__ deg, const int* __restrict__ coff,
                             int* __restrict__ rp, int* __restrict__ cur, int n) {
    __shared__ int s[256];
    int i = blockIdx.x * 256 + threadIdx.x;
    int v = (i < n) ? deg[i] : 0;
    s[threadIdx.x] = v; __syncthreads();
    for (int off = 1; off < 256; off <<= 1) {
        int x = (threadIdx.x >= off) ? s[threadIdx.x - off] : 0;
        __syncthreads();
        s[threadIdx.x] += x;
        __syncthreads();
    }
    if (i < n) {
        int r = coff[blockIdx.x] + s[threadIdx.x] - v;   // exclusive
        rp[i] = r;
        cur[i] = r;
    }
}

__global__ void k_fill(const int* __restrict__ src, const int* __restrict__ dst,
                       int* __restrict__ cur, int* __restrict__ esrc, int* __restrict__ edst, int E) {
    int e = blockIdx.x * 256 + threadIdx.x;
    if (e < E) {
        int d = dst[e];
        int p = atomicAdd(&cur[d], 1);
        esrc[p] = src[e];
        edst[p] = d;
    }
}

// ============================ weight prep (fused transposes) ============================
__global__ void k_prep(const float* __restrict__ Wx, const float* __restrict__ W0,
                       const float* __restrict__ W1, const float* __restrict__ Wf,
                       const float* __restrict__ rWf,
                       ushort* __restrict__ BtX, ushort* __restrict__ Bt0,
                       ushort* __restrict__ Bt1, ushort* __restrict__ BtF) {
    int i = blockIdx.x * 256 + threadIdx.x;
    if (i < 16384) {                         // BtX [64][256] <- Wx [256][64]
        int n = i >> 8, k = i & 255;
        BtX[i] = f2bf(Wx[k * 64 + n]);
    } else if (i < 49152) {                  // Bt0 [256][128] <- W0 [128][256]
        int t = i - 16384;
        int n = t >> 7, k = t & 127;
        Bt0[t] = f2bf(W0[k * 256 + n]);
    } else if (i < 114688) {                 // Bt1 [256][256] <- W1 [256][256]
        int t = i - 49152;
        int n = t >> 8, k = t & 255;
        Bt1[t] = f2bf(W1[k * 256 + n]);
    } else if (i < 131072) {                 // BtF [64][256] <- Wf|rWf [256][32]
        int t = i - 114688;
        int n = t >> 8, k = t & 255;
        float v = (n < 32) ? Wf[k * 32 + n] : rWf[k * 32 + (n - 32)];
        BtF[t] = f2bf(v);
    }
}

// ============================ bf16 MFMA GEMM ============================
// C[M,Nc] = A[M,K] @ B[K,Nc]; B given transposed+bf16: Bt[Nc][K].
template<bool A_F32, bool OUT_BF16, int ACT, int WR, int WC, int WM, int WN>
__global__ __launch_bounds__(256) void gemm_mfma(
    const void* __restrict__ Aptr, const ushort* __restrict__ Bt, void* __restrict__ Cptr,
    int M, int Nc, int K, const float* __restrict__ bias)
{
    constexpr int BM = WR * WM * 16;
    constexpr int BN = WC * WN * 16;
    constexpr int BK = 32;
    constexpr int LDA = BK + 8;          // pad to break bank conflicts
    __shared__ ushort As[BM][LDA];
    __shared__ ushort Bs[BN][LDA];

    const int tid = threadIdx.x;
    const int bm = blockIdx.x * BM;
    const int bn = blockIdx.y * BN;
    const int lane = tid & 63;
    const int w = tid >> 6;
    const int wr = w / WC, wc = w % WC;
    const int fr = lane & 15;
    const int kg = lane >> 4;

    f32x4 acc[WM][WN];
    #pragma unroll
    for (int i = 0; i < WM; ++i)
        #pragma unroll
        for (int j = 0; j < WN; ++j) acc[i][j] = (f32x4){0.f, 0.f, 0.f, 0.f};

    const float*  Af = (const float*)Aptr;
    const ushort* Ab = (const ushort*)Aptr;

    for (int k0 = 0; k0 < K; k0 += BK) {
        constexpr int ACH = BM * (BK / 4);
        #pragma unroll
        for (int c = tid; c < ACH; c += 256) {
            int r = c >> 3;
            int ko = (c & 7) * 4;
            int gr = bm + r;
            ushort4 o = {0, 0, 0, 0};
            if (gr < M) {
                if (A_F32) {
                    float4 v = *(const float4*)(Af + (size_t)gr * K + k0 + ko);
                    o.x = f2bf(v.x); o.y = f2bf(v.y); o.z = f2bf(v.z); o.w = f2bf(v.w);
                } else {
                    o = *(const ushort4*)(Ab + (size_t)gr * K + k0 + ko);
                }
            }
            *(ushort4*)&As[r][ko] = o;
        }
        constexpr int BCH = BN * (BK / 4);
        #pragma unroll
        for (int c = tid; c < BCH; c += 256) {
            int r = c >> 3;
            int ko = (c & 7) * 4;
            *(ushort4*)&Bs[r][ko] = *(const ushort4*)(Bt + (size_t)(bn + r) * K + k0 + ko);
        }
        __syncthreads();

        bf16x8 a[WM], b[WN];
        #pragma unroll
        for (int m = 0; m < WM; ++m)
            a[m] = *(const bf16x8*)&As[wr * WM * 16 + m * 16 + fr][kg * 8];
        #pragma unroll
        for (int n = 0; n < WN; ++n)
            b[n] = *(const bf16x8*)&Bs[wc * WN * 16 + n * 16 + fr][kg * 8];
        #pragma unroll
        for (int m = 0; m < WM; ++m)
            #pragma unroll
            for (int n = 0; n < WN; ++n)
                acc[m][n] = __builtin_amdgcn_mfma_f32_16x16x32_bf16(a[m], b[n], acc[m][n], 0, 0, 0);
        __syncthreads();
    }

    float*  Cf = (float*)Cptr;
    ushort* Cb = (ushort*)Cptr;
    #pragma unroll
    for (int m = 0; m < WM; ++m) {
        #pragma unroll
        for (int n = 0; n < WN; ++n) {
            int col = bn + wc * WN * 16 + n * 16 + fr;
            float bv = bias ? bias[col] : 0.f;
            #pragma unroll
            for (int j = 0; j < 4; ++j) {
                int row = bm + wr * WM * 16 + m * 16 + kg * 4 + j;
                if (row < M) {
                    float o = acc[m][n][j] + bv;
                    if (ACT == 1) o = fmaxf(o, 0.f);
                    if (OUT_BF16) Cb[(size_t)row * Nc + col] = f2bf(o);
                    else          Cf[(size_t)row * Nc + col] = o;
                }
            }
        }
    }
}

// ============================ node kernels ============================
__global__ __launch_bounds__(256) void k_norm(const float* __restrict__ h0, const float* __restrict__ z,
                                              ushort* __restrict__ hbuf, int n) {
    int wid = (blockIdx.x * blockDim.x + threadIdx.x) >> 6;
    int lane = threadIdx.x & 63;
    if (wid >= n) return;
    float v = h0[(size_t)wid * 64 + lane];
    float zl = z[lane];
    float ss = v * v + zl * zl;
    #pragma unroll
    for (int off = 32; off > 0; off >>= 1) ss += __shfl_xor(ss, off, 64);
    float inv = 1.f / (sqrtf(ss) + 1e-6f);
    hbuf[(size_t)wid * 128 + lane]      = f2bf(v * inv);
    hbuf[(size_t)wid * 128 + 64 + lane] = f2bf(zl * inv);
}

// el/er from bf16 feat [N,256]; one wave per node; head = lane>>5
__global__ __launch_bounds__(256) void k_eler256(const ushort* __restrict__ feat,
                                                 const float* __restrict__ al, const float* __restrict__ ar,
                                                 float* __restrict__ el, float* __restrict__ er, int n) {
    int wid = (blockIdx.x * blockDim.x + threadIdx.x) >> 6;
    int lane = threadIdx.x & 63;
    if (wid >= n) return;
    int head = lane >> 5;
    ushort4 fu = ((const ushort4*)feat)[(size_t)wid * 64 + lane];
    float4 a = ((const float4*)al)[lane];
    float4 r = ((const float4*)ar)[lane];
    float fx = bf2f(fu.x), fy = bf2f(fu.y), fz = bf2f(fu.z), fw = bf2f(fu.w);
    float pe = fx * a.x + fy * a.y + fz * a.z + fw * a.w;
    float pr = fx * r.x + fy * r.y + fz * r.z + fw * r.w;
    #pragma unroll
    for (int off = 16; off > 0; off >>= 1) {
        pe += __shfl_xor(pe, off, 64);
        pr += __shfl_xor(pr, off, 64);
    }
    if ((lane & 31) == 0) {
        el[(size_t)wid * 2 + head] = pe;
        er[(size_t)wid * 2 + head] = pr;
    }
}

// final layer: 1 head, 32 dims (pk f32 [N,64]: feat|resid)
__global__ __launch_bounds__(256) void k_elerf(const float* __restrict__ pk,
                                               const float* __restrict__ alf, const float* __restrict__ arf,
                                               float* __restrict__ elf, float* __restrict__ erf, int n) {
    int wid = (blockIdx.x * blockDim.x + threadIdx.x) >> 6;
    int lane = threadIdx.x & 63;
    if (wid >= n) return;
    float f = (lane < 32) ? pk[(size_t)wid * 64 + lane] : 0.f;
    float a = (lane < 32) ? alf[lane] : 0.f;
    float r = (lane < 32) ? arf[lane] : 0.f;
    float pe = f * a, pr = f * r;
    #pragma unroll
    for (int off = 16; off > 0; off >>= 1) {
        pe += __shfl_xor(pe, off, 64);
        pr += __shfl_xor(pr, off, 64);
    }
    if (lane == 0) { elf[wid] = pe; erf[wid] = pr; }
}

// ============================ per-edge weights (no-max softmax) ============================
// w{0,1}[e] = exp(leaky(el[src] + er[dst])) per head; edge-parallel, coalesced.
__global__ void k_xe2(const int* __restrict__ esrc, const int* __restrict__ edst,
                      const float* __restrict__ el, const float* __restrict__ er,
                      float* __restrict__ w0, float* __restrict__ w1, int E) {
    int e = blockIdx.x * 256 + threadIdx.x;
    if (e >= E) return;
    int s = esrc[e], d = edst[e];
    float2 l = ((const float2*)el)[s];
    float2 r = ((const float2*)er)[d];
    float x0 = l.x + r.x, x1 = l.y + r.y;
    x0 = (x0 > 0.f) ? x0 : NEG * x0;
    x1 = (x1 > 0.f) ? x1 : NEG * x1;
    w0[e] = __expf(fminf(x0, 60.f));
    w1[e] = __expf(fminf(x1, 60.f));
}

__global__ void k_xef(const int* __restrict__ esrc, const int* __restrict__ edst,
                      const float* __restrict__ elf, const float* __restrict__ erf,
                      float* __restrict__ wf, int E) {
    int e = blockIdx.x * 256 + threadIdx.x;
    if (e >= E) return;
    float x = elf[esrc[e]] + erf[edst[e]];
    x = (x > 0.f) ? x : NEG * x;
    wf[e] = __expf(fminf(x, 60.f));
}

// ============================ edge aggregation ============================
// One wave per dst node; precomputed weights; 32-edge chunks loaded cooperatively
// (low half loads w0, high half w1 -> width-32 shfl is automatically head-matched).
template<int RES>
__global__ __launch_bounds__(256) void k_edge256(
    const ushort* __restrict__ feat, const float* __restrict__ w0, const float* __restrict__ w1,
    const float* __restrict__ bias, const int* __restrict__ rp, const int* __restrict__ esrc,
    ushort* __restrict__ outp, const ushort* __restrict__ resid, int n)
{
    int wid = (blockIdx.x * blockDim.x + threadIdx.x) >> 6;
    int lane = threadIdx.x & 63;
    if (wid >= n) return;
    int m = lane & 31;
    int rs = rp[wid], re = rp[wid + 1];
    const float* wh = (lane >= 32) ? w1 : w0;
    const char* featc = (const char*)feat;
    uint loff = (uint)lane << 3;

    float den0 = 0.f, den1 = 0.f;
    float ax0 = 0.f, ay0 = 0.f, az0 = 0.f, aw0 = 0.f;
    float ax1 = 0.f, ay1 = 0.f, az1 = 0.f, aw1 = 0.f;

    for (int c = rs; c < re; c += 32) {
        int nj = re - c; if (nj > 32) nj = 32;
        int sv = 0; float wv = 0.f;
        if (m < nj) { sv = esrc[c + m]; wv = wh[c + m]; }
        int j = 0;
        for (; j + 1 < nj; j += 2) {
            int   sA = __shfl(sv, j, 32);
            int   sB = __shfl(sv, j + 1, 32);
            float wA = __shfl(wv, j, 32);
            float wB = __shfl(wv, j + 1, 32);
            ushort4 vA = *(const ushort4*)(featc + (((uint)sA << 9) | loff));
            ushort4 vB = *(const ushort4*)(featc + (((uint)sB << 9) | loff));
            den0 += wA;
            ax0 += wA * bf2f(vA.x); ay0 += wA * bf2f(vA.y);
            az0 += wA * bf2f(vA.z); aw0 += wA * bf2f(vA.w);
            den1 += wB;
            ax1 += wB * bf2f(vB.x); ay1 += wB * bf2f(vB.y);
            az1 += wB * bf2f(vB.z); aw1 += wB * bf2f(vB.w);
        }
        if (j < nj) {
            int   sA = __shfl(sv, j, 32);
            float wA = __shfl(wv, j, 32);
            ushort4 vA = *(const ushort4*)(featc + (((uint)sA << 9) | loff));
            den0 += wA;
            ax0 += wA * bf2f(vA.x); ay0 += wA * bf2f(vA.y);
            az0 += wA * bf2f(vA.z); aw0 += wA * bf2f(vA.w);
        }
    }
    float den = den0 + den1;
    float ax = ax0 + ax1, ay = ay0 + ay1, az = az0 + az1, aw = aw0 + aw1;
    float inv = (re > rs) ? 1.f / den : 0.f;

    int c0i = lane * 4;
    float4 bv = *(const float4*)(bias + c0i);
    float rx = 0.f, ry = 0.f, rz = 0.f, rw = 0.f;
    if (RES) {
        ushort4 rv = ((const ushort4*)resid)[(size_t)wid * 64 + lane];
        rx = bf2f(rv.x); ry = bf2f(rv.y); rz = bf2f(rv.z); rw = bf2f(rv.w);
    }
    float ox = ax * inv + bv.x + rx;
    float oy = ay * inv + bv.y + ry;
    float oz = az * inv + bv.z + rz;
    float ow = aw * inv + bv.w + rw;
    ox = (ox > 0.f) ? ox : expm1f(ox);
    oy = (oy > 0.f) ? oy : expm1f(oy);
    oz = (oz > 0.f) ? oz : expm1f(oz);
    ow = (ow > 0.f) ? ow : expm1f(ow);
    ushort4 o;
    o.x = f2bf(ox); o.y = f2bf(oy); o.z = f2bf(oz); o.w = f2bf(ow);
    ((ushort4*)outp)[(size_t)wid * 64 + lane] = o;
}

// final layer: half-wave (32 lanes) per node; 32 cols; pk f32 [N,64] = feat|resid
__global__ __launch_bounds__(256) void k_edgef(
    const float* __restrict__ pk, const float* __restrict__ wf,
    const float* __restrict__ bfv, const int* __restrict__ rp, const int* __restrict__ esrc,
    float* __restrict__ outp, int n)
{
    int node = (blockIdx.x * blockDim.x + threadIdx.x) >> 5;
    int m = threadIdx.x & 31;
    if (node >= n) return;
    int rs = rp[node], re = rp[node + 1];
    const char* pkc = (const char*)pk;
    uint moff = (uint)m << 2;

    float den0 = 0.f, den1 = 0.f, A0 = 0.f, A1 = 0.f;
    for (int c = rs; c < re; c += 32) {
        int nj = re - c; if (nj > 32) nj = 32;
        int sv = 0; float wv = 0.f;
        if (m < nj) { sv = esrc[c + m]; wv = wf[c + m]; }
        int j = 0;
        for (; j + 1 < nj; j += 2) {
            int   sA = __shfl(sv, j, 32);
            int   sB = __shfl(sv, j + 1, 32);
            float wA = __shfl(wv, j, 32);
            float wB = __shfl(wv, j + 1, 32);
            float vA = *(const float*)(pkc + (((uint)sA << 8) | moff));
            float vB = *(const float*)(pkc + (((uint)sB << 8) | moff));
            den0 += wA; A0 += wA * vA;
            den1 += wB; A1 += wB * vB;
        }
        if (j < nj) {
            int   sA = __shfl(sv, j, 32);
            float wA = __shfl(wv, j, 32);
            float vA = *(const float*)(pkc + (((uint)sA << 8) | moff));
            den0 += wA; A0 += wA * vA;
        }
    }
    float den = den0 + den1, acc = A0 + A1;
    float inv = (re > rs) ? 1.f / den : 0.f;
    outp[(size_t)node * 32 + m] = acc * inv + pk[(size_t)node * 64 + 32 + m] + bfv[m];
}

// ============================ launch ============================
extern "C" void kernel_launch(void* const* d_in, const int* in_sizes, int n_in,
                              void* d_out, int out_size, void* d_ws, size_t ws_size,
                              hipStream_t stream) {
    const float* inputs = (const float*)d_in[0];
    const float* z      = (const float*)d_in[1];
    const int*   src    = (const int*)d_in[2];
    const int*   dst    = (const int*)d_in[3];
    const float* Wx  = (const float*)d_in[4];
    const float* bx  = (const float*)d_in[5];
    const float* W0  = (const float*)d_in[6];
    const float* al0 = (const float*)d_in[7];
    const float* ar0 = (const float*)d_in[8];
    const float* b0  = (const float*)d_in[9];
    const float* W1  = (const float*)d_in[10];
    const float* al1 = (const float*)d_in[11];
    const float* ar1 = (const float*)d_in[12];
    const float* b1  = (const float*)d_in[13];
    const float* Wf  = (const float*)d_in[14];
    const float* alf = (const float*)d_in[15];
    const float* arf = (const float*)d_in[16];
    const float* bf  = (const float*)d_in[17];
    const float* rWf = (const float*)d_in[18];
    float* out = (float*)d_out;

    const int N = N_NODES, E = N_EDGES;

    char* w = (char*)d_ws;
    auto alloc = [&](size_t bytes) -> char* {
        char* p = w;
        w += (bytes + 255) & ~(size_t)255;
        return p;
    };
    ushort* hbuf = (ushort*)alloc((size_t)N * 128 * 2);
    ushort* feat = (ushort*)alloc((size_t)N * 256 * 2);
    ushort* h1   = (ushort*)alloc((size_t)N * 256 * 2);
    ushort* h2   = (ushort*)alloc((size_t)N * 256 * 2);
    float*  pk   = (float*)alloc((size_t)N * 64 * 4);
    float*  elb  = (float*)alloc((size_t)N * 2 * 4);
    float*  erb  = (float*)alloc((size_t)N * 2 * 4);
    ushort* BtX  = (ushort*)alloc((size_t)64 * 256 * 2);
    ushort* Bt0  = (ushort*)alloc((size_t)256 * 128 * 2);
    ushort* Bt1  = (ushort*)alloc((size_t)256 * 256 * 2);
    ushort* BtF  = (ushort*)alloc((size_t)64 * 256 * 2);
    int* rp   = (int*)alloc((size_t)(N + 1) * 4);
    int* deg  = (int*)alloc((size_t)N * 4);
    int* cur  = (int*)alloc((size_t)N * 4);
    int* csum = (int*)alloc(256 * 4);
    int* coff = (int*)alloc(256 * 4);
    int* esrc = (int*)alloc((size_t)E * 4);
    int* edst = (int*)alloc((size_t)E * 4);
    float* we0 = (float*)alloc((size_t)E * 4);
    float* we1 = (float*)alloc((size_t)E * 4);

    // ---- CSR by dst ----
    hipMemsetAsync(deg, 0, (size_t)N * 4, stream);
    k_hist<<<(E + 255) / 256, 256, 0, stream>>>(dst, deg, E);
    int nch = (N + 255) / 256;
    k_chunksum<<<nch, 256, 0, stream>>>(deg, csum, N);
    k_scanchunks<<<1, 256, 0, stream>>>(csum, coff, nch, rp, N, E);
    k_scatter_rp<<<nch, 256, 0, stream>>>(deg, coff, rp, cur, N);
    k_fill<<<(E + 255) / 256, 256, 0, stream>>>(src, dst, cur, esrc, edst, E);

    // ---- weight prep ----
    k_prep<<<512, 256, 0, stream>>>(Wx, W0, W1, Wf, rWf, BtX, Bt0, Bt1, BtF);

    int nwb = (N + 3) / 4;          // 1 wave/node kernels
    int nhb = (N + 7) / 8;          // half-wave/node kernels
    int neb = (E + 255) / 256;      // edge-parallel kernels
    dim3 gw((N + 127) / 128, 1);
    dim3 gb((N + 127) / 128, 2);

    // ---- x_to_h ----
    gemm_mfma<true, false, 1, 4, 1, 2, 4><<<gw, 256, 0, stream>>>(inputs, BtX, pk, N, 64, 256, bx);
    k_norm<<<nwb, 256, 0, stream>>>(pk, z, hbuf, N);

    // ---- GAT layer 0 ----
    gemm_mfma<false, true, 0, 2, 2, 4, 4><<<gb, 256, 0, stream>>>(hbuf, Bt0, feat, N, 256, 128, nullptr);
    k_eler256<<<nwb, 256, 0, stream>>>(feat, al0, ar0, elb, erb, N);
    k_xe2<<<neb, 256, 0, stream>>>(esrc, edst, elb, erb, we0, we1, E);
    k_edge256<0><<<nwb, 256, 0, stream>>>(feat, we0, we1, b0, rp, esrc, h1, nullptr, N);

    // ---- GAT layer 1 (identity residual) ----
    gemm_mfma<false, true, 0, 2, 2, 4, 4><<<gb, 256, 0, stream>>>(h1, Bt1, feat, N, 256, 256, nullptr);
    k_eler256<<<nwb, 256, 0, stream>>>(feat, al1, ar1, elb, erb, N);
    k_xe2<<<neb, 256, 0, stream>>>(esrc, edst, elb, erb, we0, we1, E);
    k_edge256<1><<<nwb, 256, 0, stream>>>(feat, we0, we1, b1, rp, esrc, h2, h1, N);

    // ---- final GAT ----
    gemm_mfma<false, false, 0, 4, 1, 2, 4><<<gw, 256, 0, stream>>>(h2, BtF, pk, N, 64, 256, nullptr);
    k_elerf<<<nwb, 256, 0, stream>>>(pk, alf, arf, elb, erb, N);
    k_xef<<<neb, 256, 0, stream>>>(esrc, edst, elb, erb, we0, E);
    k_edgef<<<nhb, 256, 0, stream>>>(pk, we0, bf, rp, esrc, out, N);
}

// Round 4
// 396.797 us; speedup vs baseline: 1.8336x; 1.0503x over previous
//
#include <hip/hip_runtime.h>
#include <hip/hip_bf16.h>
#include <math.h>

#define N_NODES 50000
#define N_EDGES 800000
#define NEG 0.2f

typedef __attribute__((ext_vector_type(4))) float f32x4;
typedef __attribute__((ext_vector_type(8))) short bf16x8;

__device__ __forceinline__ float bf2f(ushort u) {
    union { uint i; float f; } t; t.i = ((uint)u) << 16; return t.f;
}
__device__ __forceinline__ ushort f2bf(float f) {
    union { float f; uint i; } t; t.f = f;
    uint i = t.i;
    uint r = (i + 0x7FFFu + ((i >> 16) & 1u)) >> 16;   // RNE
    return (ushort)r;
}

// ============================ CSR build ============================
__global__ void k_hist(const int* __restrict__ dst, int* __restrict__ deg, int E) {
    int e = blockIdx.x * 256 + threadIdx.x;
    if (e < E) atomicAdd(&deg[dst[e]], 1);
}

__global__ void k_chunksum(const int* __restrict__ deg, int* __restrict__ csum, int n) {
    __shared__ int s[256];
    int i = blockIdx.x * 256 + threadIdx.x;
    s[threadIdx.x] = (i < n) ? deg[i] : 0;
    __syncthreads();
    for (int off = 128; off > 0; off >>= 1) {
        if (threadIdx.x < off) s[threadIdx.x] += s[threadIdx.x + off];
        __syncthreads();
    }
    if (threadIdx.x == 0) csum[blockIdx.x] = s[0];
}

__global__ void k_scanchunks(const int* __restrict__ csum, int* __restrict__ coff,
                             int nch, int* __restrict__ rp, int n, int E) {
    __shared__ int s[256];
    int t = threadIdx.x;
    int v = (t < nch) ? csum[t] : 0;
    s[t] = v; __syncthreads();
    for (int off = 1; off < 256; off <<= 1) {
        int x = (t >= off) ? s[t - off] : 0;
        __syncthreads();
        s[t] += x;
        __syncthreads();
    }
    coff[t] = s[t] - v;          // exclusive prefix of chunk sums
    if (t == 0) rp[n] = E;
}

__global__ void k_scatter_rp(const int* __restrict__ deg, const int* __restrict__ coff,
                             int* __restrict__ rp, int* __restrict__ cur, int n) {
    __shared__ int s[256];
    int i = blockIdx.x * 256 + threadIdx.x;
    int v = (i < n) ? deg[i] : 0;
    s[threadIdx.x] = v; __syncthreads();
    for (int off = 1; off < 256; off <<= 1) {
        int x = (threadIdx.x >= off) ? s[threadIdx.x - off] : 0;
        __syncthreads();
        s[threadIdx.x] += x;
        __syncthreads();
    }
    if (i < n) {
        int r = coff[blockIdx.x] + s[threadIdx.x] - v;   // exclusive
        rp[i] = r;
        cur[i] = r;
    }
}

__global__ void k_fill(const int* __restrict__ src, const int* __restrict__ dst,
                       int* __restrict__ cur, int* __restrict__ esrc, int E) {
    int e = blockIdx.x * 256 + threadIdx.x;
    if (e < E) {
        int p = atomicAdd(&cur[dst[e]], 1);
        esrc[p] = src[e];
    }
}

// ============================ weight prep (fused transposes) ============================
__global__ void k_prep(const float* __restrict__ Wx, const float* __restrict__ W0,
                       const float* __restrict__ W1, const float* __restrict__ Wf,
                       const float* __restrict__ rWf,
                       ushort* __restrict__ BtX, ushort* __restrict__ Bt0,
                       ushort* __restrict__ Bt1, ushort* __restrict__ BtF) {
    int i = blockIdx.x * 256 + threadIdx.x;
    if (i < 16384) {                         // BtX [64][256] <- Wx [256][64]
        int n = i >> 8, k = i & 255;
        BtX[i] = f2bf(Wx[k * 64 + n]);
    } else if (i < 49152) {                  // Bt0 [256][128] <- W0 [128][256]
        int t = i - 16384;
        int n = t >> 7, k = t & 127;
        Bt0[t] = f2bf(W0[k * 256 + n]);
    } else if (i < 114688) {                 // Bt1 [256][256] <- W1 [256][256]
        int t = i - 49152;
        int n = t >> 8, k = t & 255;
        Bt1[t] = f2bf(W1[k * 256 + n]);
    } else if (i < 131072) {                 // BtF [64][256] <- Wf|rWf [256][32]
        int t = i - 114688;
        int n = t >> 8, k = t & 255;
        float v = (n < 32) ? Wf[k * 32 + n] : rWf[k * 32 + (n - 32)];
        BtF[t] = f2bf(v);
    }
}

// ============================ bf16 MFMA GEMM ============================
// C[M,Nc] = A[M,K] @ B[K,Nc]; B given transposed+bf16: Bt[Nc][K].
// OMODE: 0=f32 out, 1=bf16 out, 2=bf16 out + f32 copy of cols>=32 into C2[N,32]
template<bool A_F32, int OMODE, int ACT, int WR, int WC, int WM, int WN>
__global__ __launch_bounds__(256) void gemm_mfma(
    const void* __restrict__ Aptr, const ushort* __restrict__ Bt, void* __restrict__ Cptr,
    float* __restrict__ C2, int M, int Nc, int K, const float* __restrict__ bias)
{
    constexpr int BM = WR * WM * 16;
    constexpr int BN = WC * WN * 16;
    constexpr int BK = 32;
    constexpr int LDA = BK + 8;          // pad to break bank conflicts
    __shared__ ushort As[BM][LDA];
    __shared__ ushort Bs[BN][LDA];

    const int tid = threadIdx.x;
    const int bm = blockIdx.x * BM;
    const int bn = blockIdx.y * BN;
    const int lane = tid & 63;
    const int w = tid >> 6;
    const int wr = w / WC, wc = w % WC;
    const int fr = lane & 15;
    const int kg = lane >> 4;

    f32x4 acc[WM][WN];
    #pragma unroll
    for (int i = 0; i < WM; ++i)
        #pragma unroll
        for (int j = 0; j < WN; ++j) acc[i][j] = (f32x4){0.f, 0.f, 0.f, 0.f};

    const float*  Af = (const float*)Aptr;
    const ushort* Ab = (const ushort*)Aptr;

    for (int k0 = 0; k0 < K; k0 += BK) {
        constexpr int ACH = BM * (BK / 4);
        #pragma unroll
        for (int c = tid; c < ACH; c += 256) {
            int r = c >> 3;
            int ko = (c & 7) * 4;
            int gr = bm + r;
            ushort4 o = {0, 0, 0, 0};
            if (gr < M) {
                if (A_F32) {
                    float4 v = *(const float4*)(Af + (size_t)gr * K + k0 + ko);
                    o.x = f2bf(v.x); o.y = f2bf(v.y); o.z = f2bf(v.z); o.w = f2bf(v.w);
                } else {
                    o = *(const ushort4*)(Ab + (size_t)gr * K + k0 + ko);
                }
            }
            *(ushort4*)&As[r][ko] = o;
        }
        constexpr int BCH = BN * (BK / 4);
        #pragma unroll
        for (int c = tid; c < BCH; c += 256) {
            int r = c >> 3;
            int ko = (c & 7) * 4;
            *(ushort4*)&Bs[r][ko] = *(const ushort4*)(Bt + (size_t)(bn + r) * K + k0 + ko);
        }
        __syncthreads();

        bf16x8 a[WM], b[WN];
        #pragma unroll
        for (int m = 0; m < WM; ++m)
            a[m] = *(const bf16x8*)&As[wr * WM * 16 + m * 16 + fr][kg * 8];
        #pragma unroll
        for (int n = 0; n < WN; ++n)
            b[n] = *(const bf16x8*)&Bs[wc * WN * 16 + n * 16 + fr][kg * 8];
        #pragma unroll
        for (int m = 0; m < WM; ++m)
            #pragma unroll
            for (int n = 0; n < WN; ++n)
                acc[m][n] = __builtin_amdgcn_mfma_f32_16x16x32_bf16(a[m], b[n], acc[m][n], 0, 0, 0);
        __syncthreads();
    }

    float*  Cf = (float*)Cptr;
    ushort* Cb = (ushort*)Cptr;
    #pragma unroll
    for (int m = 0; m < WM; ++m) {
        #pragma unroll
        for (int n = 0; n < WN; ++n) {
            int col = bn + wc * WN * 16 + n * 16 + fr;
            float bv = bias ? bias[col] : 0.f;
            #pragma unroll
            for (int j = 0; j < 4; ++j) {
                int row = bm + wr * WM * 16 + m * 16 + kg * 4 + j;
                if (row < M) {
                    float o = acc[m][n][j] + bv;
                    if (ACT == 1) o = fmaxf(o, 0.f);
                    if (OMODE == 0) {
                        Cf[(size_t)row * Nc + col] = o;
                    } else if (OMODE == 1) {
                        Cb[(size_t)row * Nc + col] = f2bf(o);
                    } else {
                        Cb[(size_t)row * Nc + col] = f2bf(o);
                        if (col >= 32) C2[(size_t)row * 32 + (col - 32)] = o;
                    }
                }
            }
        }
    }
}

// ============================ node kernels ============================
__global__ __launch_bounds__(256) void k_norm(const float* __restrict__ h0, const float* __restrict__ z,
                                              ushort* __restrict__ hbuf, int n) {
    int wid = (blockIdx.x * blockDim.x + threadIdx.x) >> 6;
    int lane = threadIdx.x & 63;
    if (wid >= n) return;
    float v = h0[(size_t)wid * 64 + lane];
    float zl = z[lane];
    float ss = v * v + zl * zl;
    #pragma unroll
    for (int off = 32; off > 0; off >>= 1) ss += __shfl_xor(ss, off, 64);
    float inv = 1.f / (sqrtf(ss) + 1e-6f);
    hbuf[(size_t)wid * 128 + lane]      = f2bf(v * inv);
    hbuf[(size_t)wid * 128 + 64 + lane] = f2bf(zl * inv);
}

// el/er from bf16 feat [N,256]; one wave per node; head = lane>>5
__global__ __launch_bounds__(256) void k_eler256(const ushort* __restrict__ feat,
                                                 const float* __restrict__ al, const float* __restrict__ ar,
                                                 float* __restrict__ el, float* __restrict__ er, int n) {
    int wid = (blockIdx.x * blockDim.x + threadIdx.x) >> 6;
    int lane = threadIdx.x & 63;
    if (wid >= n) return;
    int head = lane >> 5;
    ushort4 fu = ((const ushort4*)feat)[(size_t)wid * 64 + lane];
    float4 a = ((const float4*)al)[lane];
    float4 r = ((const float4*)ar)[lane];
    float fx = bf2f(fu.x), fy = bf2f(fu.y), fz = bf2f(fu.z), fw = bf2f(fu.w);
    float pe = fx * a.x + fy * a.y + fz * a.z + fw * a.w;
    float pr = fx * r.x + fy * r.y + fz * r.z + fw * r.w;
    #pragma unroll
    for (int off = 16; off > 0; off >>= 1) {
        pe += __shfl_xor(pe, off, 64);
        pr += __shfl_xor(pr, off, 64);
    }
    if ((lane & 31) == 0) {
        el[(size_t)wid * 2 + head] = pe;
        er[(size_t)wid * 2 + head] = pr;
    }
}

// final layer: 1 head, 32 dims; pkb bf16 [N,64] = featf|resid
__global__ __launch_bounds__(256) void k_elerf(const ushort* __restrict__ pkb,
                                               const float* __restrict__ alf, const float* __restrict__ arf,
                                               float* __restrict__ elf, float* __restrict__ erf, int n) {
    int wid = (blockIdx.x * blockDim.x + threadIdx.x) >> 6;
    int lane = threadIdx.x & 63;
    if (wid >= n) return;
    float f = (lane < 32) ? bf2f(pkb[(size_t)wid * 64 + lane]) : 0.f;
    float a = (lane < 32) ? alf[lane] : 0.f;
    float r = (lane < 32) ? arf[lane] : 0.f;
    float pe = f * a, pr = f * r;
    #pragma unroll
    for (int off = 16; off > 0; off >>= 1) {
        pe += __shfl_xor(pe, off, 64);
        pr += __shfl_xor(pr, off, 64);
    }
    if (lane == 0) { elf[wid] = pe; erf[wid] = pr; }
}

// ============================ edge aggregation ============================
// One wave per dst node. Per 32-edge chunk, lane m computes its edge's softmax
// weight (fused: exp(leaky(el[src]+er[dst])), head = lane>>5), then width-32
// shfl broadcasts (s,w). 4 gathers in flight (4 independent accumulator sets).
template<int RES>
__global__ __launch_bounds__(256) void k_edge256(
    const ushort* __restrict__ feat, const float* __restrict__ el, const float* __restrict__ er,
    const float* __restrict__ bias, const int* __restrict__ rp, const int* __restrict__ esrc,
    ushort* __restrict__ outp, const ushort* __restrict__ resid, int n)
{
    int wid = (blockIdx.x * blockDim.x + threadIdx.x) >> 6;
    int lane = threadIdx.x & 63;
    if (wid >= n) return;
    int m = lane & 31;
    int head = lane >> 5;
    int rs = rp[wid], re = rp[wid + 1];
    float ern = er[((size_t)wid << 1) + head];
    const char* featc = (const char*)feat;
    uint loff = (uint)lane << 3;

    float den[4] = {0.f, 0.f, 0.f, 0.f};
    f32x4 av[4];
    #pragma unroll
    for (int u = 0; u < 4; ++u) av[u] = (f32x4){0.f, 0.f, 0.f, 0.f};

    for (int c = rs; c < re; c += 32) {
        int nj = re - c; if (nj > 32) nj = 32;
        int sv = 0; float wv = 0.f;
        if (m < nj) {
            sv = esrc[c + m];
            float x = el[((uint)sv << 1) + head] + ern;
            x = (x > 0.f) ? x : NEG * x;
            wv = __expf(fminf(x, 60.f));
        }
        int j = 0;
        for (; j + 3 < nj; j += 4) {
            #pragma unroll
            for (int u = 0; u < 4; ++u) {
                int   sU = __shfl(sv, j + u, 32);
                float wU = __shfl(wv, j + u, 32);
                ushort4 vU = *(const ushort4*)(featc + (((uint)sU << 9) | loff));
                den[u] += wU;
                av[u].x += wU * bf2f(vU.x);
                av[u].y += wU * bf2f(vU.y);
                av[u].z += wU * bf2f(vU.z);
                av[u].w += wU * bf2f(vU.w);
            }
        }
        for (; j < nj; ++j) {
            int   sU = __shfl(sv, j, 32);
            float wU = __shfl(wv, j, 32);
            ushort4 vU = *(const ushort4*)(featc + (((uint)sU << 9) | loff));
            den[0] += wU;
            av[0].x += wU * bf2f(vU.x);
            av[0].y += wU * bf2f(vU.y);
            av[0].z += wU * bf2f(vU.z);
            av[0].w += wU * bf2f(vU.w);
        }
    }
    float denT = (den[0] + den[1]) + (den[2] + den[3]);
    float ax = (av[0].x + av[1].x) + (av[2].x + av[3].x);
    float ay = (av[0].y + av[1].y) + (av[2].y + av[3].y);
    float az = (av[0].z + av[1].z) + (av[2].z + av[3].z);
    float aw = (av[0].w + av[1].w) + (av[2].w + av[3].w);
    float inv = (re > rs) ? 1.f / denT : 0.f;

    int c0i = lane * 4;
    float4 bv = *(const float4*)(bias + c0i);
    float rx = 0.f, ry = 0.f, rz = 0.f, rw = 0.f;
    if (RES) {
        ushort4 rv = ((const ushort4*)resid)[(size_t)wid * 64 + lane];
        rx = bf2f(rv.x); ry = bf2f(rv.y); rz = bf2f(rv.z); rw = bf2f(rv.w);
    }
    float ox = ax * inv + bv.x + rx;
    float oy = ay * inv + bv.y + ry;
    float oz = az * inv + bv.z + rz;
    float ow = aw * inv + bv.w + rw;
    ox = (ox > 0.f) ? ox : expm1f(ox);
    oy = (oy > 0.f) ? oy : expm1f(oy);
    oz = (oz > 0.f) ? oz : expm1f(oz);
    ow = (ow > 0.f) ? ow : expm1f(ow);
    ushort4 o;
    o.x = f2bf(ox); o.y = f2bf(oy); o.z = f2bf(oz); o.w = f2bf(ow);
    ((ushort4*)outp)[(size_t)wid * 64 + lane] = o;
}

// final layer: 16 lanes per node (4 nodes/wave); lane covers 2 cols (ushort2
// gather from pkb rows, 64 B/edge); fused weights; 4-deep pipeline.
__global__ __launch_bounds__(256) void k_edgef(
    const ushort* __restrict__ pkb, const float* __restrict__ residf,
    const float* __restrict__ elf, const float* __restrict__ erf,
    const float* __restrict__ bfv, const int* __restrict__ rp, const int* __restrict__ esrc,
    float* __restrict__ outp, int n)
{
    int t = blockIdx.x * 256 + threadIdx.x;
    int node = t >> 4;
    int m = t & 15;
    if (node >= n) return;
    int rs = rp[node], re = rp[node + 1];
    float ern = erf[node];
    const char* pc = (const char*)pkb;
    uint moff = (uint)m << 2;

    float den[4] = {0.f, 0.f, 0.f, 0.f};
    float a0[4] = {0.f, 0.f, 0.f, 0.f};
    float a1[4] = {0.f, 0.f, 0.f, 0.f};

    for (int c = rs; c < re; c += 16) {
        int nj = re - c; if (nj > 16) nj = 16;
        int sv = 0; float wv = 0.f;
        if (m < nj) {
            sv = esrc[c + m];
            float x = elf[sv] + ern;
            x = (x > 0.f) ? x : NEG * x;
            wv = __expf(fminf(x, 60.f));
        }
        int j = 0;
        for (; j + 3 < nj; j += 4) {
            #pragma unroll
            for (int u = 0; u < 4; ++u) {
                int   sU = __shfl(sv, j + u, 16);
                float wU = __shfl(wv, j + u, 16);
                ushort2 vU = *(const ushort2*)(pc + (((uint)sU << 7) | moff));
                den[u] += wU;
                a0[u] += wU * bf2f(vU.x);
                a1[u] += wU * bf2f(vU.y);
            }
        }
        for (; j < nj; ++j) {
            int   sU = __shfl(sv, j, 16);
            float wU = __shfl(wv, j, 16);
            ushort2 vU = *(const ushort2*)(pc + (((uint)sU << 7) | moff));
            den[0] += wU;
            a0[0] += wU * bf2f(vU.x);
            a1[0] += wU * bf2f(vU.y);
        }
    }
    float dT = (den[0] + den[1]) + (den[2] + den[3]);
    float A0 = (a0[0] + a0[1]) + (a0[2] + a0[3]);
    float A1 = (a1[0] + a1[1]) + (a1[2] + a1[3]);
    float inv = (re > rs) ? 1.f / dT : 0.f;

    float2 rv = *(const float2*)(residf + (size_t)node * 32 + 2 * m);
    float2 bv = *(const float2*)(bfv + 2 * m);
    float2 o;
    o.x = A0 * inv + rv.x + bv.x;
    o.y = A1 * inv + rv.y + bv.y;
    *(float2*)(outp + (size_t)node * 32 + 2 * m) = o;
}

// ============================ launch ============================
extern "C" void kernel_launch(void* const* d_in, const int* in_sizes, int n_in,
                              void* d_out, int out_size, void* d_ws, size_t ws_size,
                              hipStream_t stream) {
    const float* inputs = (const float*)d_in[0];
    const float* z      = (const float*)d_in[1];
    const int*   src    = (const int*)d_in[2];
    const int*   dst    = (const int*)d_in[3];
    const float* Wx  = (const float*)d_in[4];
    const float* bx  = (const float*)d_in[5];
    const float* W0  = (const float*)d_in[6];
    const float* al0 = (const float*)d_in[7];
    const float* ar0 = (const float*)d_in[8];
    const float* b0  = (const float*)d_in[9];
    const float* W1  = (const float*)d_in[10];
    const float* al1 = (const float*)d_in[11];
    const float* ar1 = (const float*)d_in[12];
    const float* b1  = (const float*)d_in[13];
    const float* Wf  = (const float*)d_in[14];
    const float* alf = (const float*)d_in[15];
    const float* arf = (const float*)d_in[16];
    const float* bf  = (const float*)d_in[17];
    const float* rWf = (const float*)d_in[18];
    float* out = (float*)d_out;

    const int N = N_NODES, E = N_EDGES;

    char* w = (char*)d_ws;
    auto alloc = [&](size_t bytes) -> char* {
        char* p = w;
        w += (bytes + 255) & ~(size_t)255;
        return p;
    };
    ushort* hbuf  = (ushort*)alloc((size_t)N * 128 * 2);
    ushort* feat  = (ushort*)alloc((size_t)N * 256 * 2);
    ushort* h1    = (ushort*)alloc((size_t)N * 256 * 2);
    ushort* h2    = (ushort*)alloc((size_t)N * 256 * 2);
    ushort* pkb   = (ushort*)alloc((size_t)N * 64 * 2);   // featf|resid bf16
    float*  residf= (float*)alloc((size_t)N * 32 * 4);    // resid f32
    float*  elb   = (float*)alloc((size_t)N * 2 * 4);
    float*  erb   = (float*)alloc((size_t)N * 2 * 4);
    ushort* BtX   = (ushort*)alloc((size_t)64 * 256 * 2);
    ushort* Bt0   = (ushort*)alloc((size_t)256 * 128 * 2);
    ushort* Bt1   = (ushort*)alloc((size_t)256 * 256 * 2);
    ushort* BtF   = (ushort*)alloc((size_t)64 * 256 * 2);
    int* rp   = (int*)alloc((size_t)(N + 1) * 4);
    int* deg  = (int*)alloc((size_t)N * 4);
    int* cur  = (int*)alloc((size_t)N * 4);
    int* csum = (int*)alloc(256 * 4);
    int* coff = (int*)alloc(256 * 4);
    int* esrc = (int*)alloc((size_t)E * 4);
    float* pk = (float*)feat;   // x_to_h f32 output aliases feat (dead before layer-0 GEMM)

    // ---- CSR by dst ----
    hipMemsetAsync(deg, 0, (size_t)N * 4, stream);
    k_hist<<<(E + 255) / 256, 256, 0, stream>>>(dst, deg, E);
    int nch = (N + 255) / 256;
    k_chunksum<<<nch, 256, 0, stream>>>(deg, csum, N);
    k_scanchunks<<<1, 256, 0, stream>>>(csum, coff, nch, rp, N, E);
    k_scatter_rp<<<nch, 256, 0, stream>>>(deg, coff, rp, cur, N);
    k_fill<<<(E + 255) / 256, 256, 0, stream>>>(src, dst, cur, esrc, E);

    // ---- weight prep ----
    k_prep<<<512, 256, 0, stream>>>(Wx, W0, W1, Wf, rWf, BtX, Bt0, Bt1, BtF);

    int nwb = (N + 3) / 4;          // 1 wave/node kernels
    dim3 gw((N + 127) / 128, 1);
    dim3 gb((N + 127) / 128, 2);

    // ---- x_to_h ----
    gemm_mfma<true, 0, 1, 4, 1, 2, 4><<<gw, 256, 0, stream>>>(inputs, BtX, pk, nullptr, N, 64, 256, bx);
    k_norm<<<nwb, 256, 0, stream>>>(pk, z, hbuf, N);

    // ---- GAT layer 0 ----
    gemm_mfma<false, 1, 0, 2, 2, 4, 4><<<gb, 256, 0, stream>>>(hbuf, Bt0, feat, nullptr, N, 256, 128, nullptr);
    k_eler256<<<nwb, 256, 0, stream>>>(feat, al0, ar0, elb, erb, N);
    k_edge256<0><<<nwb, 256, 0, stream>>>(feat, elb, erb, b0, rp, esrc, h1, nullptr, N);

    // ---- GAT layer 1 (identity residual) ----
    gemm_mfma<false, 1, 0, 2, 2, 4, 4><<<gb, 256, 0, stream>>>(h1, Bt1, feat, nullptr, N, 256, 256, nullptr);
    k_eler256<<<nwb, 256, 0, stream>>>(feat, al1, ar1, elb, erb, N);
    k_edge256<1><<<nwb, 256, 0, stream>>>(feat, elb, erb, b1, rp, esrc, h2, h1, N);

    // ---- final GAT: [N,256] -> 32 + linear residual ----
    gemm_mfma<false, 2, 0, 4, 1, 2, 4><<<gw, 256, 0, stream>>>(h2, BtF, pkb, residf, N, 64, 256, nullptr);
    k_elerf<<<nwb, 256, 0, stream>>>(pkb, alf, arf, elb, erb, N);
    k_edgef<<<(N + 15) / 16, 256, 0, stream>>>(pkb, residf, elb, erb, bf, rp, esrc, out, N);
}

// Round 5
// 369.384 us; speedup vs baseline: 1.9697x; 1.0742x over previous
//
#include <hip/hip_runtime.h>
#include <hip/hip_bf16.h>
#include <math.h>

#define N_NODES 50000
#define N_EDGES 800000
#define NEG 0.2f

typedef __attribute__((ext_vector_type(4))) float f32x4;
typedef __attribute__((ext_vector_type(8))) short bf16x8;

__device__ __forceinline__ float bf2f(ushort u) {
    union { uint i; float f; } t; t.i = ((uint)u) << 16; return t.f;
}
__device__ __forceinline__ ushort f2bf(float f) {
    union { float f; uint i; } t; t.f = f;
    uint i = t.i;
    uint r = (i + 0x7FFFu + ((i >> 16) & 1u)) >> 16;   // RNE
    return (ushort)r;
}

// async global->LDS, 16B per lane; dst wave-uniform, src per-lane
__device__ __forceinline__ void gload16(const ushort* src, ushort* ldst) {
    __builtin_amdgcn_global_load_lds(
        (const __attribute__((address_space(1))) uint32_t*)src,
        (__attribute__((address_space(3))) uint32_t*)ldst, 16, 0, 0);
}

// ============================ CSR build ============================
__global__ void k_hist(const int* __restrict__ dst, int* __restrict__ deg, int E) {
    int e = blockIdx.x * 256 + threadIdx.x;
    if (e < E) atomicAdd(&deg[dst[e]], 1);
}

__global__ void k_chunksum(const int* __restrict__ deg, int* __restrict__ csum, int n) {
    __shared__ int s[256];
    int i = blockIdx.x * 256 + threadIdx.x;
    s[threadIdx.x] = (i < n) ? deg[i] : 0;
    __syncthreads();
    for (int off = 128; off > 0; off >>= 1) {
        if (threadIdx.x < off) s[threadIdx.x] += s[threadIdx.x + off];
        __syncthreads();
    }
    if (threadIdx.x == 0) csum[blockIdx.x] = s[0];
}

__global__ void k_scanchunks(const int* __restrict__ csum, int* __restrict__ coff,
                             int nch, int* __restrict__ rp, int n, int E) {
    __shared__ int s[256];
    int t = threadIdx.x;
    int v = (t < nch) ? csum[t] : 0;
    s[t] = v; __syncthreads();
    for (int off = 1; off < 256; off <<= 1) {
        int x = (t >= off) ? s[t - off] : 0;
        __syncthreads();
        s[t] += x;
        __syncthreads();
    }
    coff[t] = s[t] - v;          // exclusive prefix of chunk sums
    if (t == 0) rp[n] = E;
}

__global__ void k_scatter_rp(const int* __restrict__ deg, const int* __restrict__ coff,
                             int* __restrict__ rp, int* __restrict__ cur, int n) {
    __shared__ int s[256];
    int i = blockIdx.x * 256 + threadIdx.x;
    int v = (i < n) ? deg[i] : 0;
    s[threadIdx.x] = v; __syncthreads();
    for (int off = 1; off < 256; off <<= 1) {
        int x = (threadIdx.x >= off) ? s[threadIdx.x - off] : 0;
        __syncthreads();
        s[threadIdx.x] += x;
        __syncthreads();
    }
    if (i < n) {
        int r = coff[blockIdx.x] + s[threadIdx.x] - v;   // exclusive
        rp[i] = r;
        cur[i] = r;
    }
}

__global__ void k_fill(const int* __restrict__ src, const int* __restrict__ dst,
                       int* __restrict__ cur, int* __restrict__ esrc, int E) {
    int e = blockIdx.x * 256 + threadIdx.x;
    if (e < E) {
        int p = atomicAdd(&cur[dst[e]], 1);
        esrc[p] = src[e];
    }
}

// ============================ weight prep (fused transposes) ============================
__global__ void k_prep(const float* __restrict__ Wx, const float* __restrict__ W0,
                       const float* __restrict__ W1, const float* __restrict__ Wf,
                       const float* __restrict__ rWf,
                       ushort* __restrict__ BtX, ushort* __restrict__ Bt0,
                       ushort* __restrict__ Bt1, ushort* __restrict__ BtF) {
    int i = blockIdx.x * 256 + threadIdx.x;
    if (i < 16384) {                         // BtX [64][256] <- Wx [256][64]
        int n = i >> 8, k = i & 255;
        BtX[i] = f2bf(Wx[k * 64 + n]);
    } else if (i < 49152) {                  // Bt0 [256][128] <- W0 [128][256]
        int t = i - 16384;
        int n = t >> 7, k = t & 127;
        Bt0[t] = f2bf(W0[k * 256 + n]);
    } else if (i < 114688) {                 // Bt1 [256][256] <- W1 [256][256]
        int t = i - 49152;
        int n = t >> 8, k = t & 255;
        Bt1[t] = f2bf(W1[k * 256 + n]);
    } else if (i < 131072) {                 // BtF [64][256] <- Wf|rWf [256][32]
        int t = i - 114688;
        int n = t >> 8, k = t & 255;
        float v = (n < 32) ? Wf[k * 32 + n] : rWf[k * 32 + (n - 32)];
        BtF[t] = f2bf(v);
    }
}

// inputs f32 [N*256] -> bf16
__global__ void k_cvt(const float* __restrict__ in, ushort* __restrict__ out, int n8) {
    int i = blockIdx.x * 256 + threadIdx.x;
    if (i >= n8) return;
    float4 v0 = ((const float4*)in)[2 * i];
    float4 v1 = ((const float4*)in)[2 * i + 1];
    ushort4 a, b;
    a.x = f2bf(v0.x); a.y = f2bf(v0.y); a.z = f2bf(v0.z); a.w = f2bf(v0.w);
    b.x = f2bf(v1.x); b.y = f2bf(v1.y); b.z = f2bf(v1.z); b.w = f2bf(v1.w);
    ((ushort4*)out)[2 * i]     = a;
    ((ushort4*)out)[2 * i + 1] = b;
}

// ============================ bf16 MFMA GEMM (global_load_lds staging) ============================
// C[M,Nc] = A[M,K] @ B[K,Nc]; A bf16 [M][K], B transposed bf16: Bt[Nc][K].
// BM=128, BK=64. LDS linear; source inverse-swizzled; ds_read XOR-swizzled (T2/G21).
// OMODE: 0=f32 out, 1=bf16 out, 2=bf16 out + f32 copy of cols>=32 into C2[N,32]
template<int OMODE, int ACT, int WR, int WC, int WM, int WN>
__global__ __launch_bounds__(256) void gemm_glds(
    const ushort* __restrict__ A, const ushort* __restrict__ Bt, void* __restrict__ Cptr,
    float* __restrict__ C2, int M, int Nc, int K, const float* __restrict__ bias)
{
    constexpr int BM = WR * WM * 16;       // 128
    constexpr int BN = WC * WN * 16;       // 64 or 128
    constexpr int BK = 64;
    static_assert(BM == 128, "BM must be 128");
    __shared__ ushort As[BM * BK];         // row-major [128][64], swizzled blocks
    __shared__ ushort Bs[BN * BK];

    const int tid = threadIdx.x;
    const int bm = blockIdx.x * BM;
    const int bn = blockIdx.y * BN;
    const int lane = tid & 63;
    const int w = tid >> 6;
    const int wr = w / WC, wc = w % WC;
    const int fr = lane & 15;
    const int kg = lane >> 4;

    f32x4 acc[WM][WN];
    #pragma unroll
    for (int i = 0; i < WM; ++i)
        #pragma unroll
        for (int j = 0; j < WN; ++j) acc[i][j] = (f32x4){0.f, 0.f, 0.f, 0.f};

    const int rl = lane >> 3;              // row within 8-row group
    const int bl = lane & 7;               // 16B block within row

    for (int k0 = 0; k0 < K; k0 += BK) {
        // ---- stage A: 16 instrs, 4 per wave; instr i covers rows i*8..i*8+7 ----
        #pragma unroll
        for (int i = w; i < 16; i += 4) {
            int r = i * 8 + rl;
            int cb = bl ^ (r & 7);         // inverse swizzle on SOURCE
            int gr = bm + r;
            if (gr >= M) gr = 0;           // clamp (rows >= M never stored)
            gload16(A + (size_t)gr * K + k0 + cb * 8, &As[i * 512]);
        }
        // ---- stage B: BN/8 instrs ----
        #pragma unroll
        for (int i = w; i < BN / 8; i += 4) {
            int r = i * 8 + rl;
            int cb = bl ^ (r & 7);
            gload16(Bt + (size_t)(bn + r) * K + k0 + cb * 8, &Bs[i * 512]);
        }
        __syncthreads();   // drains vmcnt (incl. global_load_lds) before reads

        #pragma unroll
        for (int s = 0; s < 2; ++s) {      // two K=32 substeps per BK=64 tile
            bf16x8 a[WM], b[WN];
            #pragma unroll
            for (int m = 0; m < WM; ++m) {
                int row = wr * WM * 16 + m * 16 + fr;
                int blk = (s * 4 + kg) ^ (fr & 7);   // swizzled READ
                a[m] = *(const bf16x8*)&As[row * 64 + blk * 8];
            }
            #pragma unroll
            for (int n = 0; n < WN; ++n) {
                int row = wc * WN * 16 + n * 16 + fr;
                int blk = (s * 4 + kg) ^ (fr & 7);
                b[n] = *(const bf16x8*)&Bs[row * 64 + blk * 8];
            }
            #pragma unroll
            for (int m = 0; m < WM; ++m)
                #pragma unroll
                for (int n = 0; n < WN; ++n)
                    acc[m][n] = __builtin_amdgcn_mfma_f32_16x16x32_bf16(a[m], b[n], acc[m][n], 0, 0, 0);
        }
        __syncthreads();
    }

    // ---- epilogue: C/D layout col=lane&15, row=(lane>>4)*4+j ----
    float*  Cf = (float*)Cptr;
    ushort* Cb = (ushort*)Cptr;
    #pragma unroll
    for (int m = 0; m < WM; ++m) {
        #pragma unroll
        for (int n = 0; n < WN; ++n) {
            int col = bn + wc * WN * 16 + n * 16 + fr;
            float bv = bias ? bias[col] : 0.f;
            #pragma unroll
            for (int j = 0; j < 4; ++j) {
                int row = bm + wr * WM * 16 + m * 16 + kg * 4 + j;
                if (row < M) {
                    float o = acc[m][n][j] + bv;
                    if (ACT == 1) o = fmaxf(o, 0.f);
                    if (OMODE == 0) {
                        Cf[(size_t)row * Nc + col] = o;
                    } else if (OMODE == 1) {
                        Cb[(size_t)row * Nc + col] = f2bf(o);
                    } else {
                        Cb[(size_t)row * Nc + col] = f2bf(o);
                        if (col >= 32) C2[(size_t)row * 32 + (col - 32)] = o;
                    }
                }
            }
        }
    }
}

// ============================ node kernels ============================
__global__ __launch_bounds__(256) void k_norm(const float* __restrict__ h0, const float* __restrict__ z,
                                              ushort* __restrict__ hbuf, int n) {
    int wid = (blockIdx.x * blockDim.x + threadIdx.x) >> 6;
    int lane = threadIdx.x & 63;
    if (wid >= n) return;
    float v = h0[(size_t)wid * 64 + lane];
    float zl = z[lane];
    float ss = v * v + zl * zl;
    #pragma unroll
    for (int off = 32; off > 0; off >>= 1) ss += __shfl_xor(ss, off, 64);
    float inv = 1.f / (sqrtf(ss) + 1e-6f);
    hbuf[(size_t)wid * 128 + lane]      = f2bf(v * inv);
    hbuf[(size_t)wid * 128 + 64 + lane] = f2bf(zl * inv);
}

// el/er from bf16 feat [N,256]; one wave per node; head = lane>>5
__global__ __launch_bounds__(256) void k_eler256(const ushort* __restrict__ feat,
                                                 const float* __restrict__ al, const float* __restrict__ ar,
                                                 float* __restrict__ el, float* __restrict__ er, int n) {
    int wid = (blockIdx.x * blockDim.x + threadIdx.x) >> 6;
    int lane = threadIdx.x & 63;
    if (wid >= n) return;
    int head = lane >> 5;
    ushort4 fu = ((const ushort4*)feat)[(size_t)wid * 64 + lane];
    float4 a = ((const float4*)al)[lane];
    float4 r = ((const float4*)ar)[lane];
    float fx = bf2f(fu.x), fy = bf2f(fu.y), fz = bf2f(fu.z), fw = bf2f(fu.w);
    float pe = fx * a.x + fy * a.y + fz * a.z + fw * a.w;
    float pr = fx * r.x + fy * r.y + fz * r.z + fw * r.w;
    #pragma unroll
    for (int off = 16; off > 0; off >>= 1) {
        pe += __shfl_xor(pe, off, 64);
        pr += __shfl_xor(pr, off, 64);
    }
    if ((lane & 31) == 0) {
        el[(size_t)wid * 2 + head] = pe;
        er[(size_t)wid * 2 + head] = pr;
    }
}

// final layer: 1 head, 32 dims; pkb bf16 [N,64] = featf|resid
__global__ __launch_bounds__(256) void k_elerf(const ushort* __restrict__ pkb,
                                               const float* __restrict__ alf, const float* __restrict__ arf,
                                               float* __restrict__ elf, float* __restrict__ erf, int n) {
    int wid = (blockIdx.x * blockDim.x + threadIdx.x) >> 6;
    int lane = threadIdx.x & 63;
    if (wid >= n) return;
    float f = (lane < 32) ? bf2f(pkb[(size_t)wid * 64 + lane]) : 0.f;
    float a = (lane < 32) ? alf[lane] : 0.f;
    float r = (lane < 32) ? arf[lane] : 0.f;
    float pe = f * a, pr = f * r;
    #pragma unroll
    for (int off = 16; off > 0; off >>= 1) {
        pe += __shfl_xor(pe, off, 64);
        pr += __shfl_xor(pr, off, 64);
    }
    if (lane == 0) { elf[wid] = pe; erf[wid] = pr; }
}

// ============================ edge aggregation ============================
// One wave per dst node. Per 32-edge chunk, lane m computes its edge's softmax
// weight (fused: exp(leaky(el[src]+er[dst])), head = lane>>5), then width-32
// shfl broadcasts (s,w). 4 gathers in flight (4 independent accumulator sets).
template<int RES>
__global__ __launch_bounds__(256) void k_edge256(
    const ushort* __restrict__ feat, const float* __restrict__ el, const float* __restrict__ er,
    const float* __restrict__ bias, const int* __restrict__ rp, const int* __restrict__ esrc,
    ushort* __restrict__ outp, const ushort* __restrict__ resid, int n)
{
    int wid = (blockIdx.x * blockDim.x + threadIdx.x) >> 6;
    int lane = threadIdx.x & 63;
    if (wid >= n) return;
    int m = lane & 31;
    int head = lane >> 5;
    int rs = rp[wid], re = rp[wid + 1];
    float ern = er[((size_t)wid << 1) + head];
    const char* featc = (const char*)feat;
    uint loff = (uint)lane << 3;

    float den[4] = {0.f, 0.f, 0.f, 0.f};
    f32x4 av[4];
    #pragma unroll
    for (int u = 0; u < 4; ++u) av[u] = (f32x4){0.f, 0.f, 0.f, 0.f};

    for (int c = rs; c < re; c += 32) {
        int nj = re - c; if (nj > 32) nj = 32;
        int sv = 0; float wv = 0.f;
        if (m < nj) {
            sv = esrc[c + m];
            float x = el[((uint)sv << 1) + head] + ern;
            x = (x > 0.f) ? x : NEG * x;
            wv = __expf(fminf(x, 60.f));
        }
        int j = 0;
        for (; j + 3 < nj; j += 4) {
            #pragma unroll
            for (int u = 0; u < 4; ++u) {
                int   sU = __shfl(sv, j + u, 32);
                float wU = __shfl(wv, j + u, 32);
                ushort4 vU = *(const ushort4*)(featc + (((uint)sU << 9) | loff));
                den[u] += wU;
                av[u].x += wU * bf2f(vU.x);
                av[u].y += wU * bf2f(vU.y);
                av[u].z += wU * bf2f(vU.z);
                av[u].w += wU * bf2f(vU.w);
            }
        }
        for (; j < nj; ++j) {
            int   sU = __shfl(sv, j, 32);
            float wU = __shfl(wv, j, 32);
            ushort4 vU = *(const ushort4*)(featc + (((uint)sU << 9) | loff));
            den[0] += wU;
            av[0].x += wU * bf2f(vU.x);
            av[0].y += wU * bf2f(vU.y);
            av[0].z += wU * bf2f(vU.z);
            av[0].w += wU * bf2f(vU.w);
        }
    }
    float denT = (den[0] + den[1]) + (den[2] + den[3]);
    float ax = (av[0].x + av[1].x) + (av[2].x + av[3].x);
    float ay = (av[0].y + av[1].y) + (av[2].y + av[3].y);
    float az = (av[0].z + av[1].z) + (av[2].z + av[3].z);
    float aw = (av[0].w + av[1].w) + (av[2].w + av[3].w);
    float inv = (re > rs) ? 1.f / denT : 0.f;

    int c0i = lane * 4;
    float4 bv = *(const float4*)(bias + c0i);
    float rx = 0.f, ry = 0.f, rz = 0.f, rw = 0.f;
    if (RES) {
        ushort4 rv = ((const ushort4*)resid)[(size_t)wid * 64 + lane];
        rx = bf2f(rv.x); ry = bf2f(rv.y); rz = bf2f(rv.z); rw = bf2f(rv.w);
    }
    float ox = ax * inv + bv.x + rx;
    float oy = ay * inv + bv.y + ry;
    float oz = az * inv + bv.z + rz;
    float ow = aw * inv + bv.w + rw;
    ox = (ox > 0.f) ? ox : expm1f(ox);
    oy = (oy > 0.f) ? oy : expm1f(oy);
    oz = (oz > 0.f) ? oz : expm1f(oz);
    ow = (ow > 0.f) ? ow : expm1f(ow);
    ushort4 o;
    o.x = f2bf(ox); o.y = f2bf(oy); o.z = f2bf(oz); o.w = f2bf(ow);
    ((ushort4*)outp)[(size_t)wid * 64 + lane] = o;
}

// final layer: 16 lanes per node (4 nodes/wave); lane covers 2 cols (ushort2
// gather from pkb rows, 64 B/edge); fused weights; 4-deep pipeline.
__global__ __launch_bounds__(256) void k_edgef(
    const ushort* __restrict__ pkb, const float* __restrict__ residf,
    const float* __restrict__ elf, const float* __restrict__ erf,
    const float* __restrict__ bfv, const int* __restrict__ rp, const int* __restrict__ esrc,
    float* __restrict__ outp, int n)
{
    int t = blockIdx.x * 256 + threadIdx.x;
    int node = t >> 4;
    int m = t & 15;
    if (node >= n) return;
    int rs = rp[node], re = rp[node + 1];
    float ern = erf[node];
    const char* pc = (const char*)pkb;
    uint moff = (uint)m << 2;

    float den[4] = {0.f, 0.f, 0.f, 0.f};
    float a0[4] = {0.f, 0.f, 0.f, 0.f};
    float a1[4] = {0.f, 0.f, 0.f, 0.f};

    for (int c = rs; c < re; c += 16) {
        int nj = re - c; if (nj > 16) nj = 16;
        int sv = 0; float wv = 0.f;
        if (m < nj) {
            sv = esrc[c + m];
            float x = elf[sv] + ern;
            x = (x > 0.f) ? x : NEG * x;
            wv = __expf(fminf(x, 60.f));
        }
        int j = 0;
        for (; j + 3 < nj; j += 4) {
            #pragma unroll
            for (int u = 0; u < 4; ++u) {
                int   sU = __shfl(sv, j + u, 16);
                float wU = __shfl(wv, j + u, 16);
                ushort2 vU = *(const ushort2*)(pc + (((uint)sU << 7) | moff));
                den[u] += wU;
                a0[u] += wU * bf2f(vU.x);
                a1[u] += wU * bf2f(vU.y);
            }
        }
        for (; j < nj; ++j) {
            int   sU = __shfl(sv, j, 16);
            float wU = __shfl(wv, j, 16);
            ushort2 vU = *(const ushort2*)(pc + (((uint)sU << 7) | moff));
            den[0] += wU;
            a0[0] += wU * bf2f(vU.x);
            a1[0] += wU * bf2f(vU.y);
        }
    }
    float dT = (den[0] + den[1]) + (den[2] + den[3]);
    float A0 = (a0[0] + a0[1]) + (a0[2] + a0[3]);
    float A1 = (a1[0] + a1[1]) + (a1[2] + a1[3]);
    float inv = (re > rs) ? 1.f / dT : 0.f;

    float2 rv = *(const float2*)(residf + (size_t)node * 32 + 2 * m);
    float2 bv = *(const float2*)(bfv + 2 * m);
    float2 o;
    o.x = A0 * inv + rv.x + bv.x;
    o.y = A1 * inv + rv.y + bv.y;
    *(float2*)(outp + (size_t)node * 32 + 2 * m) = o;
}

// ============================ launch ============================
extern "C" void kernel_launch(void* const* d_in, const int* in_sizes, int n_in,
                              void* d_out, int out_size, void* d_ws, size_t ws_size,
                              hipStream_t stream) {
    const float* inputs = (const float*)d_in[0];
    const float* z      = (const float*)d_in[1];
    const int*   src    = (const int*)d_in[2];
    const int*   dst    = (const int*)d_in[3];
    const float* Wx  = (const float*)d_in[4];
    const float* bx  = (const float*)d_in[5];
    const float* W0  = (const float*)d_in[6];
    const float* al0 = (const float*)d_in[7];
    const float* ar0 = (const float*)d_in[8];
    const float* b0  = (const float*)d_in[9];
    const float* W1  = (const float*)d_in[10];
    const float* al1 = (const float*)d_in[11];
    const float* ar1 = (const float*)d_in[12];
    const float* b1  = (const float*)d_in[13];
    const float* Wf  = (const float*)d_in[14];
    const float* alf = (const float*)d_in[15];
    const float* arf = (const float*)d_in[16];
    const float* bf  = (const float*)d_in[17];
    const float* rWf = (const float*)d_in[18];
    float* out = (float*)d_out;

    const int N = N_NODES, E = N_EDGES;

    char* w = (char*)d_ws;
    auto alloc = [&](size_t bytes) -> char* {
        char* p = w;
        w += (bytes + 255) & ~(size_t)255;
        return p;
    };
    ushort* Ab    = (ushort*)alloc((size_t)N * 256 * 2);  // inputs bf16
    ushort* hbuf  = (ushort*)alloc((size_t)N * 128 * 2);
    ushort* feat  = (ushort*)alloc((size_t)N * 256 * 2);
    ushort* h1    = (ushort*)alloc((size_t)N * 256 * 2);
    ushort* h2    = (ushort*)alloc((size_t)N * 256 * 2);
    ushort* pkb   = (ushort*)alloc((size_t)N * 64 * 2);   // featf|resid bf16
    float*  residf= (float*)alloc((size_t)N * 32 * 4);    // resid f32
    float*  elb   = (float*)alloc((size_t)N * 2 * 4);
    float*  erb   = (float*)alloc((size_t)N * 2 * 4);
    ushort* BtX   = (ushort*)alloc((size_t)64 * 256 * 2);
    ushort* Bt0   = (ushort*)alloc((size_t)256 * 128 * 2);
    ushort* Bt1   = (ushort*)alloc((size_t)256 * 256 * 2);
    ushort* BtF   = (ushort*)alloc((size_t)64 * 256 * 2);
    int* rp   = (int*)alloc((size_t)(N + 1) * 4);
    int* deg  = (int*)alloc((size_t)N * 4);
    int* cur  = (int*)alloc((size_t)N * 4);
    int* csum = (int*)alloc(256 * 4);
    int* coff = (int*)alloc(256 * 4);
    int* esrc = (int*)alloc((size_t)E * 4);
    float* pk = (float*)feat;   // x_to_h f32 output aliases feat (dead before layer-0 GEMM)

    // ---- CSR by dst ----
    hipMemsetAsync(deg, 0, (size_t)N * 4, stream);
    k_hist<<<(E + 255) / 256, 256, 0, stream>>>(dst, deg, E);
    int nch = (N + 255) / 256;
    k_chunksum<<<nch, 256, 0, stream>>>(deg, csum, N);
    k_scanchunks<<<1, 256, 0, stream>>>(csum, coff, nch, rp, N, E);
    k_scatter_rp<<<nch, 256, 0, stream>>>(deg, coff, rp, cur, N);
    k_fill<<<(E + 255) / 256, 256, 0, stream>>>(src, dst, cur, esrc, E);

    // ---- weight prep + input convert ----
    k_prep<<<512, 256, 0, stream>>>(Wx, W0, W1, Wf, rWf, BtX, Bt0, Bt1, BtF);
    k_cvt<<<(N * 32 + 255) / 256, 256, 0, stream>>>(inputs, Ab, N * 32);   // N*256/8 groups

    int nwb = (N + 3) / 4;          // 1 wave/node kernels
    dim3 gw((N + 127) / 128, 1);
    dim3 gb((N + 127) / 128, 2);

    // ---- x_to_h ----
    gemm_glds<0, 1, 4, 1, 2, 4><<<gw, 256, 0, stream>>>(Ab, BtX, pk, nullptr, N, 64, 256, bx);
    k_norm<<<nwb, 256, 0, stream>>>(pk, z, hbuf, N);

    // ---- GAT layer 0 ----
    gemm_glds<1, 0, 2, 2, 4, 4><<<gb, 256, 0, stream>>>(hbuf, Bt0, feat, nullptr, N, 256, 128, nullptr);
    k_eler256<<<nwb, 256, 0, stream>>>(feat, al0, ar0, elb, erb, N);
    k_edge256<0><<<nwb, 256, 0, stream>>>(feat, elb, erb, b0, rp, esrc, h1, nullptr, N);

    // ---- GAT layer 1 (identity residual) ----
    gemm_glds<1, 0, 2, 2, 4, 4><<<gb, 256, 0, stream>>>(h1, Bt1, feat, nullptr, N, 256, 256, nullptr);
    k_eler256<<<nwb, 256, 0, stream>>>(feat, al1, ar1, elb, erb, N);
    k_edge256<1><<<nwb, 256, 0, stream>>>(feat, elb, erb, b1, rp, esrc, h2, h1, N);

    // ---- final GAT: [N,256] -> 32 + linear residual ----
    gemm_glds<2, 0, 4, 1, 2, 4><<<gw, 256, 0, stream>>>(h2, BtF, pkb, residf, N, 64, 256, nullptr);
    k_elerf<<<nwb, 256, 0, stream>>>(pkb, alf, arf, elb, erb, N);
    k_edgef<<<(N + 15) / 16, 256, 0, stream>>>(pkb, residf, elb, erb, bf, rp, esrc, out, N);
}

// Round 6
// 344.094 us; speedup vs baseline: 2.1145x; 1.0735x over previous
//
#include <hip/hip_runtime.h>
#include <hip/hip_bf16.h>
#include <math.h>

#define N_NODES 50000
#define N_EDGES 800000
#define NEG 0.2f

typedef __attribute__((ext_vector_type(4))) float f32x4;
typedef __attribute__((ext_vector_type(8))) short bf16x8;

__device__ __forceinline__ float bf2f(ushort u) {
    union { uint i; float f; } t; t.i = ((uint)u) << 16; return t.f;
}
__device__ __forceinline__ ushort f2bf(float f) {
    union { float f; uint i; } t; t.f = f;
    uint i = t.i;
    uint r = (i + 0x7FFFu + ((i >> 16) & 1u)) >> 16;   // RNE
    return (ushort)r;
}

// async global->LDS, 16B per lane; dst wave-uniform, src per-lane
__device__ __forceinline__ void gload16(const ushort* src, ushort* ldst) {
    __builtin_amdgcn_global_load_lds(
        (const __attribute__((address_space(1))) uint32_t*)src,
        (__attribute__((address_space(3))) uint32_t*)ldst, 16, 0, 0);
}

// ============================ CSR build ============================
__global__ void k_hist(const int* __restrict__ dst, int* __restrict__ deg, int E) {
    int e = blockIdx.x * 256 + threadIdx.x;
    if (e < E) atomicAdd(&deg[dst[e]], 1);
}

__global__ void k_chunksum(const int* __restrict__ deg, int* __restrict__ csum, int n) {
    __shared__ int s[256];
    int i = blockIdx.x * 256 + threadIdx.x;
    s[threadIdx.x] = (i < n) ? deg[i] : 0;
    __syncthreads();
    for (int off = 128; off > 0; off >>= 1) {
        if (threadIdx.x < off) s[threadIdx.x] += s[threadIdx.x + off];
        __syncthreads();
    }
    if (threadIdx.x == 0) csum[blockIdx.x] = s[0];
}

__global__ void k_scanchunks(const int* __restrict__ csum, int* __restrict__ coff,
                             int nch, int* __restrict__ rp, int n, int E) {
    __shared__ int s[256];
    int t = threadIdx.x;
    int v = (t < nch) ? csum[t] : 0;
    s[t] = v; __syncthreads();
    for (int off = 1; off < 256; off <<= 1) {
        int x = (t >= off) ? s[t - off] : 0;
        __syncthreads();
        s[t] += x;
        __syncthreads();
    }
    coff[t] = s[t] - v;          // exclusive prefix of chunk sums
    if (t == 0) rp[n] = E;
}

__global__ void k_scatter_rp(const int* __restrict__ deg, const int* __restrict__ coff,
                             int* __restrict__ rp, int* __restrict__ cur, int n) {
    __shared__ int s[256];
    int i = blockIdx.x * 256 + threadIdx.x;
    int v = (i < n) ? deg[i] : 0;
    s[threadIdx.x] = v; __syncthreads();
    for (int off = 1; off < 256; off <<= 1) {
        int x = (threadIdx.x >= off) ? s[threadIdx.x - off] : 0;
        __syncthreads();
        s[threadIdx.x] += x;
        __syncthreads();
    }
    if (i < n) {
        int r = coff[blockIdx.x] + s[threadIdx.x] - v;   // exclusive
        rp[i] = r;
        cur[i] = r;
    }
}

__global__ void k_fill(const int* __restrict__ src, const int* __restrict__ dst,
                       int* __restrict__ cur, int* __restrict__ esrc, int E) {
    int e = blockIdx.x * 256 + threadIdx.x;
    if (e < E) {
        int p = atomicAdd(&cur[dst[e]], 1);
        esrc[p] = src[e];
    }
}

// ============================ prep: weight transposes + input f32->bf16 ============================
__global__ void k_prep2(const float* __restrict__ Wx, const float* __restrict__ W0,
                        const float* __restrict__ W1, const float* __restrict__ Wf,
                        const float* __restrict__ rWf, const float* __restrict__ inputs,
                        ushort* __restrict__ BtX, ushort* __restrict__ Bt0,
                        ushort* __restrict__ Bt1, ushort* __restrict__ BtF,
                        ushort* __restrict__ Ab) {
    int i = blockIdx.x * 256 + threadIdx.x;
    if (i < 16384) {                         // BtX [64][256] <- Wx [256][64]
        int n = i >> 8, k = i & 255;
        BtX[i] = f2bf(Wx[k * 64 + n]);
    } else if (i < 49152) {                  // Bt0 [256][128] <- W0 [128][256]
        int t = i - 16384;
        int n = t >> 7, k = t & 127;
        Bt0[t] = f2bf(W0[k * 256 + n]);
    } else if (i < 114688) {                 // Bt1 [256][256] <- W1 [256][256]
        int t = i - 49152;
        int n = t >> 8, k = t & 255;
        Bt1[t] = f2bf(W1[k * 256 + n]);
    } else if (i < 131072) {                 // BtF [64][256] <- Wf|rWf [256][32]
        int t = i - 114688;
        int n = t >> 8, k = t & 255;
        float v = (n < 32) ? Wf[k * 32 + n] : rWf[k * 32 + (n - 32)];
        BtF[t] = f2bf(v);
    } else {                                 // inputs f32 -> bf16, 8 per thread
        int t = i - 131072;
        if (t < N_NODES * 32) {
            float4 v0 = ((const float4*)inputs)[2 * t];
            float4 v1 = ((const float4*)inputs)[2 * t + 1];
            ushort4 a, b;
            a.x = f2bf(v0.x); a.y = f2bf(v0.y); a.z = f2bf(v0.z); a.w = f2bf(v0.w);
            b.x = f2bf(v1.x); b.y = f2bf(v1.y); b.z = f2bf(v1.z); b.w = f2bf(v1.w);
            ((ushort4*)Ab)[2 * t]     = a;
            ((ushort4*)Ab)[2 * t + 1] = b;
        }
    }
}

// ============================ bf16 MFMA GEMM (global_load_lds staging, fused epilogues) ============================
// C = A[M,K] @ Bt[Nc][K]^T, bf16 in, f32 acc. BM=128, BK=64.
// EPI=1 (x_to_h): +bias, relu, concat-z, L2-normalize -> Cptr=hbuf bf16 [M][128]; alv=z[64].
// EPI=2 (GAT):    Cptr=feat bf16 [M][Nc=256]; el/er partial dots -> atomicAdd elv/erv [M][2]; head=blockIdx.y.
// EPI=3 (final):  Cptr=pkb bf16 [M][64]; cols>=32 also f32 -> C2 [M][32]; elf/erf direct store (alv/arv=[32]).
template<int EPI, int WR, int WC, int WM, int WN>
__global__ __launch_bounds__(256) void gemm_glds(
    const ushort* __restrict__ A, const ushort* __restrict__ Bt, void* __restrict__ Cptr,
    float* __restrict__ C2, int M, int Nc, int K, const float* __restrict__ bias,
    const float* __restrict__ alv, const float* __restrict__ arv,
    float* __restrict__ elv, float* __restrict__ erv)
{
    constexpr int BM = WR * WM * 16;       // 128
    constexpr int BN = WC * WN * 16;       // 64 or 128
    constexpr int BK = 64;
    static_assert(BM == 128, "BM must be 128");
    __shared__ ushort As[BM * BK];         // row-major [128][64], swizzled 16B blocks
    __shared__ ushort Bs[BN * BK];

    const int tid = threadIdx.x;
    const int bm = blockIdx.x * BM;
    const int bn = blockIdx.y * BN;
    const int lane = tid & 63;
    const int w = tid >> 6;
    const int wr = w / WC, wc = w % WC;
    const int fr = lane & 15;
    const int kg = lane >> 4;

    f32x4 acc[WM][WN];
    #pragma unroll
    for (int i = 0; i < WM; ++i)
        #pragma unroll
        for (int j = 0; j < WN; ++j) acc[i][j] = (f32x4){0.f, 0.f, 0.f, 0.f};

    const int rl = lane >> 3;              // row within 8-row group
    const int bl = lane & 7;               // 16B block within row

    for (int k0 = 0; k0 < K; k0 += BK) {
        #pragma unroll
        for (int i = w; i < 16; i += 4) {  // stage A
            int r = i * 8 + rl;
            int cb = bl ^ (r & 7);         // inverse swizzle on SOURCE
            int gr = bm + r;
            if (gr >= M) gr = 0;
            gload16(A + (size_t)gr * K + k0 + cb * 8, &As[i * 512]);
        }
        #pragma unroll
        for (int i = w; i < BN / 8; i += 4) {  // stage B
            int r = i * 8 + rl;
            int cb = bl ^ (r & 7);
            gload16(Bt + (size_t)(bn + r) * K + k0 + cb * 8, &Bs[i * 512]);
        }
        __syncthreads();   // drains vmcnt before LDS reads

        #pragma unroll
        for (int s = 0; s < 2; ++s) {
            bf16x8 a[WM], b[WN];
            #pragma unroll
            for (int m = 0; m < WM; ++m) {
                int row = wr * WM * 16 + m * 16 + fr;
                int blk = (s * 4 + kg) ^ (fr & 7);   // swizzled READ
                a[m] = *(const bf16x8*)&As[row * 64 + blk * 8];
            }
            #pragma unroll
            for (int n = 0; n < WN; ++n) {
                int row = wc * WN * 16 + n * 16 + fr;
                int blk = (s * 4 + kg) ^ (fr & 7);
                b[n] = *(const bf16x8*)&Bs[row * 64 + blk * 8];
            }
            #pragma unroll
            for (int m = 0; m < WM; ++m)
                #pragma unroll
                for (int n = 0; n < WN; ++n)
                    acc[m][n] = __builtin_amdgcn_mfma_f32_16x16x32_bf16(a[m], b[n], acc[m][n], 0, 0, 0);
        }
        __syncthreads();
    }

    // ---- fused epilogues; C/D layout col=lane&15, row=(lane>>4)*4+j ----
    ushort* Cb = (ushort*)Cptr;

    if (EPI == 1) {
        float zl = alv[lane];
        float zq = zl * zl;
        #pragma unroll
        for (int off = 32; off > 0; off >>= 1) zq += __shfl_xor(zq, off, 64);
        float zc[WN];
        #pragma unroll
        for (int n = 0; n < WN; ++n) zc[n] = alv[n * 16 + fr];
        #pragma unroll
        for (int m = 0; m < WM; ++m) {
            #pragma unroll
            for (int j = 0; j < 4; ++j) {
                int row = bm + wr * WM * 16 + m * 16 + kg * 4 + j;
                float v[WN]; float ss = 0.f;
                #pragma unroll
                for (int n = 0; n < WN; ++n) {
                    float o = acc[m][n][j] + bias[n * 16 + fr];
                    o = fmaxf(o, 0.f);
                    v[n] = o; ss += o * o;
                }
                #pragma unroll
                for (int off = 8; off > 0; off >>= 1) ss += __shfl_xor(ss, off, 64);
                float inv = 1.f / (sqrtf(ss + zq) + 1e-6f);
                if (row < M) {
                    #pragma unroll
                    for (int n = 0; n < WN; ++n) {
                        int col = n * 16 + fr;
                        Cb[(size_t)row * 128 + col]      = f2bf(v[n] * inv);
                        Cb[(size_t)row * 128 + 64 + col] = f2bf(zc[n] * inv);
                    }
                }
            }
        }
    } else if (EPI == 2) {
        int head = blockIdx.y;
        #pragma unroll
        for (int m = 0; m < WM; ++m) {
            #pragma unroll
            for (int j = 0; j < 4; ++j) {
                int row = bm + wr * WM * 16 + m * 16 + kg * 4 + j;
                float pe = 0.f, pr = 0.f;
                if (row < M) {
                    #pragma unroll
                    for (int n = 0; n < WN; ++n) {
                        int col = bn + wc * WN * 16 + n * 16 + fr;
                        float o = acc[m][n][j];
                        Cb[(size_t)row * Nc + col] = f2bf(o);
                        pe += o * alv[col];
                        pr += o * arv[col];
                    }
                }
                #pragma unroll
                for (int off = 8; off > 0; off >>= 1) {
                    pe += __shfl_xor(pe, off, 64);
                    pr += __shfl_xor(pr, off, 64);
                }
                if (row < M && fr == 0) {     // exactly 2 adds per (row,head): wc=0,1 -> deterministic
                    atomicAdd(&elv[(size_t)row * 2 + head], pe);
                    atomicAdd(&erv[(size_t)row * 2 + head], pr);
                }
            }
        }
    } else {   // EPI == 3
        #pragma unroll
        for (int m = 0; m < WM; ++m) {
            #pragma unroll
            for (int j = 0; j < 4; ++j) {
                int row = bm + wr * WM * 16 + m * 16 + kg * 4 + j;
                float pe = 0.f, pr = 0.f;
                if (row < M) {
                    #pragma unroll
                    for (int n = 0; n < WN; ++n) {
                        int col = n * 16 + fr;
                        float o = acc[m][n][j];
                        Cb[(size_t)row * 64 + col] = f2bf(o);
                        if (n >= 2) {
                            C2[(size_t)row * 32 + (col - 32)] = o;
                        } else {
                            pe += o * alv[col];
                            pr += o * arv[col];
                        }
                    }
                }
                #pragma unroll
                for (int off = 8; off > 0; off >>= 1) {
                    pe += __shfl_xor(pe, off, 64);
                    pr += __shfl_xor(pr, off, 64);
                }
                if (row < M && fr == 0) { elv[row] = pe; erv[row] = pr; }
            }
        }
    }
}

// ============================ edge aggregation ============================
// One wave per dst node. Per 32-edge chunk, lane m computes its edge's softmax
// weight (exp(leaky(el[src]+er[dst])), head = lane>>5), width-32 shfl broadcasts
// (s,w). 4 gathers in flight (4 independent accumulator sets).
template<int RES>
__global__ __launch_bounds__(256) void k_edge256(
    const ushort* __restrict__ feat, const float* __restrict__ el, const float* __restrict__ er,
    const float* __restrict__ bias, const int* __restrict__ rp, const int* __restrict__ esrc,
    ushort* __restrict__ outp, const ushort* __restrict__ resid, int n)
{
    int wid = (blockIdx.x * blockDim.x + threadIdx.x) >> 6;
    int lane = threadIdx.x & 63;
    if (wid >= n) return;
    int m = lane & 31;
    int head = lane >> 5;
    int rs = rp[wid], re = rp[wid + 1];
    float ern = er[((size_t)wid << 1) + head];
    const char* featc = (const char*)feat;
    uint loff = (uint)lane << 3;

    float den[4] = {0.f, 0.f, 0.f, 0.f};
    f32x4 av[4];
    #pragma unroll
    for (int u = 0; u < 4; ++u) av[u] = (f32x4){0.f, 0.f, 0.f, 0.f};

    for (int c = rs; c < re; c += 32) {
        int nj = re - c; if (nj > 32) nj = 32;
        int sv = 0; float wv = 0.f;
        if (m < nj) {
            sv = esrc[c + m];
            float x = el[((uint)sv << 1) + head] + ern;
            x = (x > 0.f) ? x : NEG * x;
            wv = __expf(fminf(x, 60.f));
        }
        int j = 0;
        for (; j + 3 < nj; j += 4) {
            #pragma unroll
            for (int u = 0; u < 4; ++u) {
                int   sU = __shfl(sv, j + u, 32);
                float wU = __shfl(wv, j + u, 32);
                ushort4 vU = *(const ushort4*)(featc + (((uint)sU << 9) | loff));
                den[u] += wU;
                av[u].x += wU * bf2f(vU.x);
                av[u].y += wU * bf2f(vU.y);
                av[u].z += wU * bf2f(vU.z);
                av[u].w += wU * bf2f(vU.w);
            }
        }
        for (; j < nj; ++j) {
            int   sU = __shfl(sv, j, 32);
            float wU = __shfl(wv, j, 32);
            ushort4 vU = *(const ushort4*)(featc + (((uint)sU << 9) | loff));
            den[0] += wU;
            av[0].x += wU * bf2f(vU.x);
            av[0].y += wU * bf2f(vU.y);
            av[0].z += wU * bf2f(vU.z);
            av[0].w += wU * bf2f(vU.w);
        }
    }
    float denT = (den[0] + den[1]) + (den[2] + den[3]);
    float ax = (av[0].x + av[1].x) + (av[2].x + av[3].x);
    float ay = (av[0].y + av[1].y) + (av[2].y + av[3].y);
    float az = (av[0].z + av[1].z) + (av[2].z + av[3].z);
    float aw = (av[0].w + av[1].w) + (av[2].w + av[3].w);
    float inv = (re > rs) ? 1.f / denT : 0.f;

    int c0i = lane * 4;
    float4 bv = *(const float4*)(bias + c0i);
    float rx = 0.f, ry = 0.f, rz = 0.f, rw = 0.f;
    if (RES) {
        ushort4 rv = ((const ushort4*)resid)[(size_t)wid * 64 + lane];
        rx = bf2f(rv.x); ry = bf2f(rv.y); rz = bf2f(rv.z); rw = bf2f(rv.w);
    }
    float ox = ax * inv + bv.x + rx;
    float oy = ay * inv + bv.y + ry;
    float oz = az * inv + bv.z + rz;
    float ow = aw * inv + bv.w + rw;
    ox = (ox > 0.f) ? ox : expm1f(ox);
    oy = (oy > 0.f) ? oy : expm1f(oy);
    oz = (oz > 0.f) ? oz : expm1f(oz);
    ow = (ow > 0.f) ? ow : expm1f(ow);
    ushort4 o;
    o.x = f2bf(ox); o.y = f2bf(oy); o.z = f2bf(oz); o.w = f2bf(ow);
    ((ushort4*)outp)[(size_t)wid * 64 + lane] = o;
}

// final layer: 16 lanes per node (4 nodes/wave); lane covers 2 cols (ushort2
// gather from pkb rows, 64 B/edge); fused weights; 4-deep pipeline.
__global__ __launch_bounds__(256) void k_edgef(
    const ushort* __restrict__ pkb, const float* __restrict__ residf,
    const float* __restrict__ elf, const float* __restrict__ erf,
    const float* __restrict__ bfv, const int* __restrict__ rp, const int* __restrict__ esrc,
    float* __restrict__ outp, int n)
{
    int t = blockIdx.x * 256 + threadIdx.x;
    int node = t >> 4;
    int m = t & 15;
    if (node >= n) return;
    int rs = rp[node], re = rp[node + 1];
    float ern = erf[node];
    const char* pc = (const char*)pkb;
    uint moff = (uint)m << 2;

    float den[4] = {0.f, 0.f, 0.f, 0.f};
    float a0[4] = {0.f, 0.f, 0.f, 0.f};
    float a1[4] = {0.f, 0.f, 0.f, 0.f};

    for (int c = rs; c < re; c += 16) {
        int nj = re - c; if (nj > 16) nj = 16;
        int sv = 0; float wv = 0.f;
        if (m < nj) {
            sv = esrc[c + m];
            float x = elf[sv] + ern;
            x = (x > 0.f) ? x : NEG * x;
            wv = __expf(fminf(x, 60.f));
        }
        int j = 0;
        for (; j + 3 < nj; j += 4) {
            #pragma unroll
            for (int u = 0; u < 4; ++u) {
                int   sU = __shfl(sv, j + u, 16);
                float wU = __shfl(wv, j + u, 16);
                ushort2 vU = *(const ushort2*)(pc + (((uint)sU << 7) | moff));
                den[u] += wU;
                a0[u] += wU * bf2f(vU.x);
                a1[u] += wU * bf2f(vU.y);
            }
        }
        for (; j < nj; ++j) {
            int   sU = __shfl(sv, j, 16);
            float wU = __shfl(wv, j, 16);
            ushort2 vU = *(const ushort2*)(pc + (((uint)sU << 7) | moff));
            den[0] += wU;
            a0[0] += wU * bf2f(vU.x);
            a1[0] += wU * bf2f(vU.y);
        }
    }
    float dT = (den[0] + den[1]) + (den[2] + den[3]);
    float A0 = (a0[0] + a0[1]) + (a0[2] + a0[3]);
    float A1 = (a1[0] + a1[1]) + (a1[2] + a1[3]);
    float inv = (re > rs) ? 1.f / dT : 0.f;

    float2 rv = *(const float2*)(residf + (size_t)node * 32 + 2 * m);
    float2 bv = *(const float2*)(bfv + 2 * m);
    float2 o;
    o.x = A0 * inv + rv.x + bv.x;
    o.y = A1 * inv + rv.y + bv.y;
    *(float2*)(outp + (size_t)node * 32 + 2 * m) = o;
}

// ============================ launch ============================
extern "C" void kernel_launch(void* const* d_in, const int* in_sizes, int n_in,
                              void* d_out, int out_size, void* d_ws, size_t ws_size,
                              hipStream_t stream) {
    const float* inputs = (const float*)d_in[0];
    const float* z      = (const float*)d_in[1];
    const int*   src    = (const int*)d_in[2];
    const int*   dst    = (const int*)d_in[3];
    const float* Wx  = (const float*)d_in[4];
    const float* bx  = (const float*)d_in[5];
    const float* W0  = (const float*)d_in[6];
    const float* al0 = (const float*)d_in[7];
    const float* ar0 = (const float*)d_in[8];
    const float* b0  = (const float*)d_in[9];
    const float* W1  = (const float*)d_in[10];
    const float* al1 = (const float*)d_in[11];
    const float* ar1 = (const float*)d_in[12];
    const float* b1  = (const float*)d_in[13];
    const float* Wf  = (const float*)d_in[14];
    const float* alf = (const float*)d_in[15];
    const float* arf = (const float*)d_in[16];
    const float* bf  = (const float*)d_in[17];
    const float* rWf = (const float*)d_in[18];
    float* out = (float*)d_out;

    const int N = N_NODES, E = N_EDGES;

    char* w = (char*)d_ws;
    auto alloc = [&](size_t bytes) -> char* {
        char* p = w;
        w += (bytes + 255) & ~(size_t)255;
        return p;
    };
    ushort* Ab    = (ushort*)alloc((size_t)N * 256 * 2);  // inputs bf16
    ushort* hbuf  = (ushort*)alloc((size_t)N * 128 * 2);
    ushort* feat  = (ushort*)alloc((size_t)N * 256 * 2);
    ushort* h1    = (ushort*)alloc((size_t)N * 256 * 2);
    ushort* h2    = (ushort*)alloc((size_t)N * 256 * 2);
    ushort* pkb   = (ushort*)alloc((size_t)N * 64 * 2);   // featf|resid bf16
    float*  residf= (float*)alloc((size_t)N * 32 * 4);    // resid f32
    float*  elerb = (float*)alloc((size_t)N * 4 * 4);     // elb [N][2] + erb [N][2], contiguous
    float*  elb   = elerb;
    float*  erb   = elerb + (size_t)N * 2;
    ushort* BtX   = (ushort*)alloc((size_t)64 * 256 * 2);
    ushort* Bt0   = (ushort*)alloc((size_t)256 * 128 * 2);
    ushort* Bt1   = (ushort*)alloc((size_t)256 * 256 * 2);
    ushort* BtF   = (ushort*)alloc((size_t)64 * 256 * 2);
    int* rp   = (int*)alloc((size_t)(N + 1) * 4);
    int* deg  = (int*)alloc((size_t)N * 4);
    int* cur  = (int*)alloc((size_t)N * 4);
    int* csum = (int*)alloc(256 * 4);
    int* coff = (int*)alloc(256 * 4);
    int* esrc = (int*)alloc((size_t)E * 4);

    // ---- CSR by dst ----
    hipMemsetAsync(deg, 0, (size_t)N * 4, stream);
    k_hist<<<(E + 255) / 256, 256, 0, stream>>>(dst, deg, E);
    int nch = (N + 255) / 256;
    k_chunksum<<<nch, 256, 0, stream>>>(deg, csum, N);
    k_scanchunks<<<1, 256, 0, stream>>>(csum, coff, nch, rp, N, E);
    k_scatter_rp<<<nch, 256, 0, stream>>>(deg, coff, rp, cur, N);
    k_fill<<<(E + 255) / 256, 256, 0, stream>>>(src, dst, cur, esrc, E);

    // ---- weight prep + input convert (one kernel) ----
    int prep_threads = 131072 + N * 32;
    k_prep2<<<(prep_threads + 255) / 256, 256, 0, stream>>>(Wx, W0, W1, Wf, rWf, inputs,
                                                            BtX, Bt0, Bt1, BtF, Ab);

    int nwb = (N + 3) / 4;          // 1 wave/node kernels
    dim3 gw((N + 127) / 128, 1);
    dim3 gb((N + 127) / 128, 2);

    // ---- x_to_h: GEMM + bias/relu/concat-z/normalize fused -> hbuf ----
    gemm_glds<1, 4, 1, 2, 4><<<gw, 256, 0, stream>>>(Ab, BtX, hbuf, nullptr, N, 64, 256, bx,
                                                     z, nullptr, nullptr, nullptr);

    // ---- GAT layer 0: GEMM + el/er fused ----
    hipMemsetAsync(elerb, 0, (size_t)N * 4 * 4, stream);
    gemm_glds<2, 2, 2, 4, 4><<<gb, 256, 0, stream>>>(hbuf, Bt0, feat, nullptr, N, 256, 128, nullptr,
                                                     al0, ar0, elb, erb);
    k_edge256<0><<<nwb, 256, 0, stream>>>(feat, elb, erb, b0, rp, esrc, h1, nullptr, N);

    // ---- GAT layer 1 (identity residual) ----
    hipMemsetAsync(elerb, 0, (size_t)N * 4 * 4, stream);
    gemm_glds<2, 2, 2, 4, 4><<<gb, 256, 0, stream>>>(h1, Bt1, feat, nullptr, N, 256, 256, nullptr,
                                                     al1, ar1, elb, erb);
    k_edge256<1><<<nwb, 256, 0, stream>>>(feat, elb, erb, b1, rp, esrc, h2, h1, N);

    // ---- final GAT: GEMM + elf/erf fused; featf|resid packed ----
    gemm_glds<3, 4, 1, 2, 4><<<gw, 256, 0, stream>>>(h2, BtF, pkb, residf, N, 64, 256, nullptr,
                                                     alf, arf, elb, erb);
    k_edgef<<<(N + 15) / 16, 256, 0, stream>>>(pkb, residf, elb, erb, bf, rp, esrc, out, N);
}